// Round 9
// baseline (625.640 us; speedup 1.0000x reference)
//
#include <hip/hip_runtime.h>
#include <hip/hip_bf16.h>
#include <math.h>

#define DIM 384
#define HEADS 6
#define NN 3136
#define BB 16
#define BH (BB*HEADS)
#define HP 58
#define NP (HP*HP)   // 3364 padded image

typedef __attribute__((ext_vector_type(8))) short short8;
typedef __attribute__((ext_vector_type(4))) short short4v;
typedef __attribute__((ext_vector_type(4))) float f32x4;

__device__ __forceinline__ float bf2f(unsigned short u) {
    union { unsigned int i; float f; } v; v.i = ((unsigned int)u) << 16; return v.f;
}
__device__ __forceinline__ unsigned short f2bf(float f) {
    union { float f; unsigned int i; } v; v.f = f;
    unsigned int r = v.i + 0x7fffu + ((v.i >> 16) & 1u);
    return (unsigned short)(r >> 16);
}
__device__ __forceinline__ void glds16(const unsigned short* g, void* l) {
    __builtin_amdgcn_global_load_lds(
        (const __attribute__((address_space(1))) unsigned int*)g,
        (__attribute__((address_space(3))) unsigned int*)l, 16, 0, 0);
}

// ---------------- fused prep: pos table (blocks 0..NN-1) + weight convert ----------------
__global__ void k_prep(const float* __restrict__ qkv_w, const float* __restrict__ proj_w,
                       const float* __restrict__ conv_w,
                       const float* __restrict__ pos_w, const float* __restrict__ pos_b,
                       unsigned short* __restrict__ Wq, unsigned short* __restrict__ Wp,
                       unsigned short* __restrict__ Wc, float* __restrict__ P) {
    int t = threadIdx.x;
    if (blockIdx.x < NN) {
        int n = blockIdx.x; int h = n / 56, w = n % 56;
        __shared__ float feat[64];
        if (t < 64) {
            int axis = t >> 5;      // 0 = y (h), 1 = x (w)
            int k = t & 31; int i = k >> 1;
            float e = (float)((axis ? w : h) + 1) / 56.000001f * 6.28318530717958647692f;
            float arg = e / powf(10000.0f, (float)i / 16.0f);
            feat[t] = (k & 1) ? cosf(arg) : sinf(arg);
        }
        __syncthreads();
        for (int c = t; c < DIM; c += 256) {
            float s = pos_b[c];
            #pragma unroll 8
            for (int k = 0; k < 64; k++) s += feat[k] * pos_w[c*64 + k];
            P[(size_t)n*DIM + c] = s;
        }
    } else {
        int tid = (blockIdx.x - NN) * 256 + t;
        int stride = 256 * 256;
        for (int i = tid; i < 3*DIM*DIM; i += stride) Wq[i] = f2bf(qkv_w[i]);
        for (int i = tid; i < DIM*DIM; i += stride) Wp[i] = f2bf(proj_w[i]);
        for (int i = tid; i < DIM*DIM*9; i += stride) {
            int ii = i % DIM; int rest = i / DIM; int tap = rest % 9; int o = rest / 9;
            Wc[i] = f2bf(conv_w[(size_t)(o*DIM + ii)*9 + tap]);
        }
    }
}

// ---------------- fused transpose + pos add + layernorm ----------------
__global__ __launch_bounds__(256) void k_tln(const float* __restrict__ x, const float* __restrict__ P,
                                             const float* __restrict__ g, const float* __restrict__ be,
                                             unsigned short* __restrict__ XTb, unsigned short* __restrict__ XN) {
    __shared__ float tile[32][388];
    int blk = blockIdx.x;
    int b = blk / 98, nt = blk % 98;
    int n0 = nt*32;
    int t = threadIdx.x;
    #pragma unroll
    for (int it = 0; it < 12; it++) {
        int task = it*256 + t;
        int c = task >> 3, seg = task & 7;
        float4 v = *reinterpret_cast<const float4*>(x + ((size_t)(b*DIM + c))*NN + n0 + seg*4);
        tile[seg*4+0][c] = v.x; tile[seg*4+1][c] = v.y;
        tile[seg*4+2][c] = v.z; tile[seg*4+3][c] = v.w;
    }
    __syncthreads();
    int row = t >> 3, sub = t & 7;
    int n = n0 + row;
    f32x4 xp[12];
    float s = 0.f;
    #pragma unroll
    for (int k = 0; k < 12; k++) {
        int c0 = (k*8 + sub)*4;
        float4 tv = *reinterpret_cast<float4*>(&tile[row][c0]);
        float4 pv = *reinterpret_cast<const float4*>(P + (size_t)n*DIM + c0);
        f32x4 xv = {tv.x+pv.x, tv.y+pv.y, tv.z+pv.z, tv.w+pv.w};
        xp[k] = xv;
        s += xv[0]+xv[1]+xv[2]+xv[3];
        unsigned short pkx[4];
        #pragma unroll
        for (int e=0;e<4;e++) pkx[e] = f2bf(xv[e]);
        *reinterpret_cast<short4v*>(XTb + ((size_t)(b*NN + n))*DIM + c0) = *(short4v*)pkx;
    }
    s += __shfl_xor(s, 1, 64); s += __shfl_xor(s, 2, 64); s += __shfl_xor(s, 4, 64);
    float mean = s * (1.0f/384.0f);
    float sq = 0.f;
    #pragma unroll
    for (int k = 0; k < 12; k++) {
        #pragma unroll
        for (int e = 0; e < 4; e++) { float d = xp[k][e]-mean; sq += d*d; }
    }
    sq += __shfl_xor(sq, 1, 64); sq += __shfl_xor(sq, 2, 64); sq += __shfl_xor(sq, 4, 64);
    float rs = rsqrtf(sq * (1.0f/384.0f) + 1e-6f);
    #pragma unroll
    for (int k = 0; k < 12; k++) {
        int c0 = (k*8 + sub)*4;
        unsigned short pk[4];
        #pragma unroll
        for (int e = 0; e < 4; e++)
            pk[e] = f2bf((xp[k][e]-mean)*rs*g[c0+e] + be[c0+e]);
        *reinterpret_cast<short4v*>(XN + ((size_t)(b*NN + n))*DIM + c0) = *(short4v*)pk;
    }
}

// ---------------- MFMA GEMM (K=384): MODE 0 = qkv, 1 = proj ----------------
// A+B dbuf via swizzled global_load_lds; counted-vmcnt raw barriers (T4).
template<int MODE>
__global__ __launch_bounds__(256) void k_gemm(
    const unsigned short* __restrict__ A, const unsigned short* __restrict__ Wt,
    const float* __restrict__ bias,
    unsigned short* __restrict__ Qb, unsigned short* __restrict__ Kb, unsigned short* __restrict__ Vt,
    const unsigned short* __restrict__ XTb, const float* __restrict__ gxca, unsigned short* __restrict__ X2p)
{
    __shared__ __align__(16) char smem[35328];
    auto ctA = (float(*)[69])smem;                     // [128][69] 35328  ([o][m])
    auto ctB = (float(*)[130])smem;                    // [64][130] 33280  ([m][o])

    constexpr int NCT = (MODE == 0) ? 9 : 3;
    constexpr int CPX = (MODE == 0) ? 441 : 147;       // 392*NCT/8
    int bid = blockIdx.x;
    int orig = (bid & 7)*CPX + (bid >> 3);
    int ct = orig % NCT, mt = orig / NCT;
    int m0 = mt*128, o0 = ct*128;
    int t = threadIdx.x;
    int wave = t >> 6, lane = t & 63;
    int wr = wave >> 1, wc = wave & 1;
    int lr = lane & 15, lg = lane >> 4;

    int r0 = t >> 2;
    int swcol = (((t & 3) ^ ((t >> 3) & 3)) << 3);
    const unsigned short* a0 = A  + (size_t)(m0 + r0)*384 + swcol;
    const unsigned short* a1 = A  + (size_t)(m0 + 64 + r0)*384 + swcol;
    const unsigned short* b0 = Wt + (size_t)(o0 + r0)*384 + swcol;
    const unsigned short* b1 = Wt + (size_t)(o0 + 64 + r0)*384 + swcol;
    int rsw = ((lr >> 1) & 3) << 3;    // read-side swizzle (shorts)

    auto stage = [&](char* base, int c) {
        glds16(a0 + c, base + wave*1024);
        glds16(a1 + c, base + 4096 + wave*1024);
        glds16(b0 + c, base + 8192 + wave*1024);
        glds16(b1 + c, base + 12288 + wave*1024);
    };

    f32x4 acc[4][4];
    #pragma unroll
    for (int i=0;i<4;i++) for (int j=0;j<4;j++) acc[i][j] = (f32x4){0.f,0.f,0.f,0.f};

    stage(smem, 0);
    for (int kk = 0; kk < 12; kk++) {
        if (kk < 11) {
            stage(smem + ((kk+1)&1)*16384, (kk+1)*32);
            asm volatile("s_waitcnt vmcnt(4)" ::: "memory");
        } else {
            asm volatile("s_waitcnt vmcnt(0)" ::: "memory");
        }
        __builtin_amdgcn_s_barrier();
        __builtin_amdgcn_sched_barrier(0);
        auto As = (unsigned short(*)[32])(smem + (kk&1)*16384);
        auto Bs = (unsigned short(*)[32])(smem + (kk&1)*16384 + 8192);
        short8 af[4], bfv[4];
        #pragma unroll
        for (int i=0;i<4;i++) af[i]  = *(short8*)&As[wr*64 + i*16 + lr][(lg*8) ^ rsw];
        #pragma unroll
        for (int j=0;j<4;j++) bfv[j] = *(short8*)&Bs[wc*64 + j*16 + lr][(lg*8) ^ rsw];
        #pragma unroll
        for (int i=0;i<4;i++)
            #pragma unroll
            for (int j=0;j<4;j++)
                acc[i][j] = __builtin_amdgcn_mfma_f32_16x16x32_bf16(af[i], bfv[j], acc[i][j], 0, 0, 0);
        __builtin_amdgcn_s_barrier();
        __builtin_amdgcn_sched_barrier(0);
    }

    // ---- epilogue ----
    int comp = (MODE == 0) ? (o0 / DIM) : 0;
    for (int mh = 0; mh < 2; mh++) {
        __syncthreads();
        bool useB = (MODE == 1) || (MODE == 0 && comp == 2);
        if (wr == mh) {
            if (useB) {
                #pragma unroll
                for (int i=0;i<4;i++) for (int j=0;j<4;j++) for (int r=0;r<4;r++)
                    ctB[i*16 + lg*4 + r][wc*64 + j*16 + lr] = acc[i][j][r];
            } else {
                #pragma unroll
                for (int i=0;i<4;i++) for (int j=0;j<4;j++) for (int r=0;r<4;r++)
                    ctA[wc*64 + j*16 + lr][i*16 + lg*4 + r] = acc[i][j][r];
            }
        }
        __syncthreads();
        if (MODE == 1) {
            for (int q = t; q < 1024; q += 256) {   // 64 m-rows x 16 o-segs(8)
                int row = q >> 4, seg = q & 15;
                int m = m0 + mh*64 + row; int b = m/NN; int n = m - b*NN;
                int py = n/56, px = n - py*56;
                int og0 = o0 + seg*8;
                short8 xvb = *(const short8*)(XTb + (size_t)m*DIM + og0);
                unsigned short pk[8];
                #pragma unroll
                for (int e=0;e<8;e++) {
                    float val = ctB[row][seg*8+e] + bias[og0+e];
                    pk[e] = f2bf(bf2f((unsigned short)xvb[e]) + gxca[og0+e]*val);
                }
                *(short8*)(X2p + ((size_t)(b*NP + (py+1)*HP + px + 1))*DIM + og0) = *(short8*)pk;
            }
        } else if (comp < 2) {                      // Q / K: (bh,dd,N) layout
            unsigned short* Dst = (comp == 0) ? Qb : Kb;
            for (int q = t; q < 2048; q += 256) {   // 128 o-rows x 16 m-segs(4)
                int row = q >> 4, seg = q & 15;
                int og = o0 + row; int rem = og - comp*DIM;
                int hh = rem >> 6, dd = rem & 63;
                int m4 = m0 + mh*64 + seg*4; int b = m4/NN; int n = m4 - b*NN;
                float bv = bias[og];
                unsigned short pk[4];
                #pragma unroll
                for (int e=0;e<4;e++) pk[e] = f2bf(ctA[row][seg*4+e] + bv);
                *(short4v*)(Dst + ((size_t)((b*HEADS + hh)*64 + dd))*NN + n) = *(short4v*)pk;
            }
        } else {                                    // V: (bh,N,dd) layout
            for (int q = t; q < 1024; q += 256) {   // 64 m-rows x 16 o-segs(8)
                int row = q >> 4, seg = q & 15;
                int m = m0 + mh*64 + row; int b = m/NN; int n = m - b*NN;
                int og0 = o0 + seg*8; int rem0 = og0 - 2*DIM;
                int hh = rem0 >> 6, dd0 = rem0 & 63;
                unsigned short pk[8];
                #pragma unroll
                for (int e=0;e<8;e++) pk[e] = f2bf(ctB[row][seg*8+e] + bias[og0+e]);
                *(short8*)(Vt + ((size_t)((b*HEADS + hh)*NN + n))*64 + dd0) = *(short8*)pk;
            }
        }
    }
}

// ---------------- conv3x3 + BN + SiLU + residual ----------------
// A-halo LDS double-buffer (glds, swizzled); B fragments in REGISTERS with
// 1-tap-deep double-buffered prefetch (compile-time parity). 13 barriers total.
#define CONV_KK(KK, PAR)                                                                   \
  {                                                                                        \
    auto Ah = (unsigned short(*)[32])(smem + ((KK)&1)*16384);                              \
    _Pragma("unroll")                                                                      \
    for (int tap = 0; tap < 9; tap++) {                                                    \
      if (tap < 8) {                                                                       \
        _Pragma("unroll")                                                                  \
        for (int j=0;j<4;j++)                                                              \
          breg[(tap+PAR+1)&1][j] = *(const short8*)(bptr[j] + (tap+1)*384 + (KK)*32);      \
      } else if ((KK) < 11) {                                                              \
        _Pragma("unroll")                                                                  \
        for (int j=0;j<4;j++)                                                              \
          breg[(tap+PAR+1)&1][j] = *(const short8*)(bptr[j] + ((KK)+1)*32);                \
      }                                                                                    \
      if (tap == 6 && (KK) < 11) stageA(((KK)+1)&1, ((KK)+1)*32);                          \
      int toff = (tap/3)*58 + (tap%3);                                                     \
      short8 af[4];                                                                        \
      _Pragma("unroll")                                                                    \
      for (int i=0;i<4;i++) {                                                              \
        int row = qrel[i] + toff;                                                          \
        af[i] = *(short8*)&Ah[row][(lg*8) ^ (((row>>1)&3)<<3)];                            \
      }                                                                                    \
      _Pragma("unroll")                                                                    \
      for (int i=0;i<4;i++)                                                                \
        _Pragma("unroll")                                                                  \
        for (int j=0;j<4;j++)                                                              \
          acc[i][j] = __builtin_amdgcn_mfma_f32_16x16x32_bf16(af[i],                       \
                        breg[(tap+PAR)&1][j], acc[i][j], 0, 0, 0);                         \
    }                                                                                      \
    asm volatile("s_waitcnt vmcnt(4)" ::: "memory");                                       \
    __builtin_amdgcn_s_barrier();                                                          \
    __builtin_amdgcn_sched_barrier(0);                                                     \
  }

__global__ __launch_bounds__(256, 3) void k_conv(
    const unsigned short* __restrict__ A, const unsigned short* __restrict__ Wt,
    const float* __restrict__ bn_g, const float* __restrict__ bn_b,
    const float* __restrict__ bn_mean, const float* __restrict__ bn_var,
    unsigned short* __restrict__ Yout)
{
    __shared__ __align__(16) char smem[32768];
    // k-loop: A halo dbuf 2x[256][32] (32KB). Epilogue aliases below.
    auto ctA = (float(*)[69])smem;                     // [64][69] 17664
    auto X2s = (unsigned short(*)[68])(smem + 17664);  // [64][68] 8704

    int bid = blockIdx.x;                 // 1200 = 8*150
    int orig = (bid & 7)*150 + (bid >> 3);
    int ct = orig % 3; int rest = orig / 3;
    int tile = rest % 25; int b = rest / 25;
    int n0 = tile*128, o0 = ct*128;
    int t = threadIdx.x;
    int wave = t >> 6, lane = t & 63;
    int wr = wave >> 1, wc = wave & 1;
    int lr = lane & 15, lg = lane >> 4;
    int qb = n0 + 2*(n0/56);
    const size_t bbase = (size_t)b*NP*DIM;

    int swcol = (((t & 3) ^ ((t >> 3) & 3)) << 3);
    // A-halo: 1024 tasks = 4/thread
    const unsigned short* asrc[4];
    #pragma unroll
    for (int j=0;j<4;j++) {
        int task = j*256 + t;
        int row = task >> 2;
        int q = qb + row; if (q > NP-1) q = NP-1;
        asrc[j] = A + bbase + (size_t)q*DIM + swcol;
    }
    // B register-fragment bases: lane's own 4 rows of Wc
    const unsigned short* bptr[4];
    #pragma unroll
    for (int j=0;j<4;j++) bptr[j] = Wt + (size_t)(o0 + wc*64 + j*16 + lr)*3456 + lg*8;

    // per-lane MFMA A row offsets (position-relative)
    int qrel[4];
    #pragma unroll
    for (int i=0;i<4;i++) {
        int loc = wr*64 + i*16 + lr;
        int n = n0 + loc; if (n >= NN) n = NN-1;
        qrel[i] = n + 2*(n/56) - qb;
    }

    auto stageA = [&](int bufsel, int c) {
        #pragma unroll
        for (int j=0;j<4;j++) glds16(asrc[j] + c, smem + bufsel*16384 + j*4096 + wave*1024);
    };

    f32x4 acc[4][4];
    #pragma unroll
    for (int i=0;i<4;i++) for (int j=0;j<4;j++) acc[i][j] = (f32x4){0.f,0.f,0.f,0.f};
    short8 breg[2][4];

    stageA(0, 0);
    #pragma unroll
    for (int j=0;j<4;j++) breg[0][j] = *(const short8*)(bptr[j]);   // kk0 tap0
    asm volatile("s_waitcnt vmcnt(0)" ::: "memory");
    __builtin_amdgcn_s_barrier();
    __builtin_amdgcn_sched_barrier(0);

    for (int kkp = 0; kkp < 6; kkp++) {
        int kk = kkp*2;
        CONV_KK(kk, 0);
        kk = kkp*2 + 1;
        CONV_KK(kk, 1);
    }

    // ---- epilogue: 4 quadrant passes (mh x oh), coalesced bf16 short8 writes ----
    for (int mh = 0; mh < 2; mh++) {
        for (int oh = 0; oh < 2; oh++) {
            __syncthreads();
            if (wr == mh && wc == oh) {
                #pragma unroll
                for (int i=0;i<4;i++) for (int j=0;j<4;j++) for (int r=0;r<4;r++)
                    ctA[j*16 + lr][i*16 + lg*4 + r] = acc[i][j][r];
            }
            for (int q = t; q < 512; q += 256) {    // residual: 64 m-rows x 8 o-segs(8)
                int row = q >> 3, sg = q & 7;
                int n = n0 + mh*64 + row; int nc = (n < NN) ? n : NN-1;
                int qq = nc + 2*(nc/56) + 59;       // center tap (+1,+1)
                short8 v = *(const short8*)(A + bbase + (size_t)qq*DIM + o0 + oh*64 + sg*8);
                short4v lo = {v[0],v[1],v[2],v[3]}, hi = {v[4],v[5],v[6],v[7]};
                *(short4v*)&X2s[row][sg*8]     = lo;
                *(short4v*)&X2s[row][sg*8 + 4] = hi;
            }
            __syncthreads();
            for (int q = t; q < 512; q += 256) {    // 64 o-rows x 8 n-segs(8)
                int orow = q >> 3, sg = q & 7;
                int o = o0 + oh*64 + orow;
                int n = n0 + mh*64 + sg*8;
                if (n < NN) {
                    float mean = bn_mean[o], rs = rsqrtf(bn_var[o] + 1e-5f);
                    float gg = bn_g[o], bb2 = bn_b[o];
                    unsigned short pk[8];
                    #pragma unroll
                    for (int e=0;e<8;e++) {
                        float xi = (ctA[orow][sg*8+e] - mean)*rs*gg + bb2;
                        float si = xi / (1.0f + __expf(-xi));
                        pk[e] = f2bf(si + bf2f(X2s[sg*8+e][orow]));
                    }
                    *(short8*)(Yout + ((size_t)(b*DIM + o))*NN + n) = *(short8*)pk;
                }
            }
        }
    }
}

// ---------------- attention stage 1: partial G = q k^T + partial sq-norms ----------------
__global__ __launch_bounds__(256) void k_qk(const unsigned short* __restrict__ Qb,
                                            const unsigned short* __restrict__ Kb,
                                            float* __restrict__ Gp, float* __restrict__ Np) {
    int cx = blockIdx.x, bh = blockIdx.y;
    int t = threadIdx.x, wave = t >> 6, lane = t & 63;
    int lr = lane & 15, lg = lane >> 4;
    {   // partial squared norms: 128 rows x 2 threads
        int row = t >> 1, p = t & 1;
        const unsigned short* src = (row < 64)
            ? Qb + ((size_t)bh*64 + row)*NN + cx*448
            : Kb + ((size_t)bh*64 + (row-64))*NN + cx*448;
        float s = 0.f;
        #pragma unroll
        for (int it = 0; it < 28; it++) {
            short8 v = *(const short8*)(src + p*224 + it*8);
            #pragma unroll
            for (int jj=0;jj<8;jj++) { float f = bf2f((unsigned short)v[jj]); s += f*f; }
        }
        s += __shfl_xor(s, 1, 64);
        if (p == 0) Np[((size_t)bh*7 + cx)*128 + row] = s;
    }
    f32x4 acc[4];
    #pragma unroll
    for (int j=0;j<4;j++) acc[j] = (f32x4){0.f,0.f,0.f,0.f};
    const unsigned short* qrow = Qb + ((size_t)bh*64 + wave*16 + lr)*NN + cx*448;
    const unsigned short* kbase = Kb + (size_t)bh*64*NN + cx*448;
    for (int ks = 0; ks < 14; ks++) {
        short8 a = *(const short8*)(qrow + ks*32 + lg*8);
        #pragma unroll
        for (int j=0;j<4;j++) {
            short8 bfr = *(const short8*)(kbase + (size_t)(j*16+lr)*NN + ks*32 + lg*8);
            acc[j] = __builtin_amdgcn_mfma_f32_16x16x32_bf16(a, bfr, acc[j], 0, 0, 0);
        }
    }
    float* gbase = Gp + ((size_t)bh*7 + cx)*4096;
    #pragma unroll
    for (int j=0;j<4;j++)
        #pragma unroll
        for (int r=0;r<4;r++)
            gbase[(wave*16 + lg*4 + r)*64 + j*16 + lr] = acc[j][r];
}

// ---------------- attention stage 2: combine + softmax -> ATT; + X2p pad-ring zero ----------------
__global__ __launch_bounds__(256) void k_sm(const float* __restrict__ Gp, const float* __restrict__ Np,
                                            const float* __restrict__ temperature,
                                            const float* __restrict__ rpb,
                                            unsigned short* __restrict__ ATT,
                                            unsigned short* __restrict__ X2p) {
    int bh = blockIdx.x; int h = bh % HEADS;
    int t = threadIdx.x;
    __shared__ float snorm[128];
    if (t < 128) {
        float s = 0.f;
        #pragma unroll
        for (int cx=0;cx<7;cx++) s += Np[((size_t)bh*7 + cx)*128 + t];
        snorm[t] = fmaxf(sqrtf(s), 1e-12f);
    }
    __syncthreads();
    int dq = t >> 2, de0 = (t & 3) * 16;
    f32x4 g[4];
    #pragma unroll
    for (int i=0;i<4;i++) g[i] = (f32x4){0.f,0.f,0.f,0.f};
    #pragma unroll
    for (int cx=0;cx<7;cx++) {
        const float* base = Gp + ((size_t)bh*7 + cx)*4096 + dq*64 + de0;
        #pragma unroll
        for (int i=0;i<4;i++) {
            float4 v = *(const float4*)(base + i*4);
            g[i][0]+=v.x; g[i][1]+=v.y; g[i][2]+=v.z; g[i][3]+=v.w;
        }
    }
    float temp = temperature[h];
    float bias = rpb[HEADS + h];
    float qn = snorm[dq];
    float lv[16]; float mx = -1e30f;
    #pragma unroll
    for (int i=0;i<4;i++)
        #pragma unroll
        for (int e=0;e<4;e++) {
            int de = de0 + i*4 + e;
            float v = g[i][e] / (qn * snorm[64 + de]) * temp + bias;
            lv[i*4+e] = v; mx = fmaxf(mx, v);
        }
    mx = fmaxf(mx, __shfl_xor(mx, 1, 64));
    mx = fmaxf(mx, __shfl_xor(mx, 2, 64));
    float se = 0.f;
    #pragma unroll
    for (int e=0;e<16;e++) { lv[e] = __expf(lv[e]-mx); se += lv[e]; }
    se += __shfl_xor(se, 1, 64);
    se += __shfl_xor(se, 2, 64);
    float inv = 1.0f/se;
    unsigned short pk[16];
    #pragma unroll
    for (int e=0;e<16;e++) pk[e] = f2bf(lv[e]*inv);
    unsigned short* dst = ATT + ((size_t)bh*64 + dq)*64 + de0;
    *(short8*)dst       = *(short8*)pk;
    *(short8*)(dst + 8) = *(short8*)(pk + 8);

    // ---- X2p pad-ring zero (Q/K dead after k_qk; 96 blocks = 16 b x 6 parts) ----
    int pb = bh / 6, part = bh % 6;
    unsigned short* base2 = X2p + (size_t)pb*NP*DIM;
    short8 z = {0,0,0,0,0,0,0,0};
    for (int task = part*256 + t; task < 10944; task += 1536) {
        int pos = task / 48, seg = task - pos*48;
        int py, px;
        if (pos < 58)       { py = 0;  px = pos; }
        else if (pos < 116) { py = 57; px = pos - 58; }
        else if (pos < 172) { py = pos - 115; px = 0; }
        else                { py = pos - 171; px = 57; }
        *(short8*)(base2 + ((size_t)(py*HP + px))*DIM + seg*8) = z;
    }
}

// ---------------- PV: XCA[b][n][h*64+dd] = sum_e ATT[dd][e] * V[e][n] ----------------
__global__ __launch_bounds__(256) void k_pv(const unsigned short* __restrict__ ATT,
                                            const unsigned short* __restrict__ Vt,
                                            unsigned short* __restrict__ XCA) {
    int nt = blockIdx.x, bh = blockIdx.y;
    int b = bh / HEADS, h = bh % HEADS;
    int t = threadIdx.x, wave = t >> 6, lane = t & 63;
    int lr = lane & 15, lg = lane >> 4;
    int n0 = nt*64;
    __shared__ float ctP[64][67];
    f32x4 acc[4];
    for (int i=0;i<4;i++) acc[i] = (f32x4){0.f,0.f,0.f,0.f};
    for (int ks=0; ks<2; ks++) {
        short8 bfr = *reinterpret_cast<const short8*>(Vt + ((size_t)bh*NN + n0 + wave*16 + lr)*64 + ks*32 + lg*8);
        for (int i=0;i<4;i++) {
            short8 a = *reinterpret_cast<const short8*>(ATT + ((size_t)bh*64 + i*16 + lr)*64 + ks*32 + lg*8);
            acc[i] = __builtin_amdgcn_mfma_f32_16x16x32_bf16(a, bfr, acc[i], 0, 0, 0);
        }
    }
    int nl = wave*16 + lr;
    #pragma unroll
    for (int i=0;i<4;i++)
        #pragma unroll
        for (int r=0;r<4;r++) ctP[nl][i*16 + lg*4 + r] = acc[i][r];
    __syncthreads();
    for (int q = t; q < 512; q += 256) {   // 64 n-rows x 8 dd-segs(8)
        int row = q >> 3, seg = q & 7;
        unsigned short pk[8];
        #pragma unroll
        for (int e=0;e<8;e++) pk[e] = f2bf(ctP[row][seg*8+e]);
        *(short8*)(XCA + ((size_t)(b*NN + n0 + row))*DIM + h*64 + seg*8) = *(short8*)pk;
    }
}

// ---------------- final: out = x + gamma-shuffled residual (Y bf16) ----------------
__global__ __launch_bounds__(256) void k_final(const float* __restrict__ x, const unsigned short* __restrict__ Yb,
                                               const float* __restrict__ gamma, float* __restrict__ out) {
    int i = blockIdx.x, b = blockIdx.y, kc = blockIdx.z;
    __shared__ float tile[56*193];
    int t = threadIdx.x;
    int k0 = kc*192;
    const unsigned short* ybase = Yb + (size_t)b*DIM*NN + (size_t)i*21504 + k0;
    for (int q = t; q < 56*24; q += 256) {
        int j = q / 24, c8 = (q % 24) * 8;
        short8 v = *(const short8*)(ybase + (size_t)j*384 + c8);
        float* dst = &tile[j*193 + c8];
        #pragma unroll
        for (int e=0;e<8;e++) dst[e] = bf2f((unsigned short)v[e]);
    }
    __syncthreads();
    for (int q = t; q < 192*56; q += 256) {
        int kl = q / 56, j = q % 56;
        int k = k0 + kl;
        size_t gi = ((size_t)(b*DIM + k))*NN + (size_t)i*56 + j;
        out[gi] = x[gi] + gamma[k] * tile[j*193 + kl];
    }
}

extern "C" void kernel_launch(void* const* d_in, const int* in_sizes, int n_in,
                              void* d_out, int out_size, void* d_ws, size_t ws_size,
                              hipStream_t stream) {
    const float* x       = (const float*)d_in[0];
    const float* pos_w   = (const float*)d_in[1];
    const float* pos_b   = (const float*)d_in[2];
    const float* ln_g    = (const float*)d_in[3];
    const float* ln_b    = (const float*)d_in[4];
    const float* gxca    = (const float*)d_in[5];
    const float* temp    = (const float*)d_in[6];
    const float* qkv_w   = (const float*)d_in[7];
    const float* qkv_b   = (const float*)d_in[8];
    const float* proj_w  = (const float*)d_in[9];
    const float* proj_b  = (const float*)d_in[10];
    const float* rpb     = (const float*)d_in[11];
    const float* conv_w  = (const float*)d_in[12];
    const float* bn_g    = (const float*)d_in[13];
    const float* bn_b    = (const float*)d_in[14];
    const float* bn_mean = (const float*)d_in[15];
    const float* bn_var  = (const float*)d_in[16];
    const float* gamma   = (const float*)d_in[17];
    float* out = (float*)d_out;
    char* ws = (char*)d_ws;

    const size_t oP   = 0;                        // P: 4,816,896 B
    const size_t oXT  = oP   + 4816896;           // XTb bf16 38.5MB (reused as Y bf16 after proj)
    const size_t oXN  = oXT  + 77070336;          // XN bf16: 38,535,168 B   (reused as Gp/Np, then XCA)
    const size_t oQ   = oXN  + 38535168;          // Qb bf16                  (reused as X2p padded, spans into Kb)
    const size_t oK   = oQ   + 38535168;          // Kb bf16
    const size_t oV   = oK   + 38535168;          // Vt bf16
    const size_t oATT = oV   + 38535168;          // ATT bf16: 786,432 B
    const size_t oWq  = oATT + 786432;            // 884,736 B
    const size_t oWp  = oWq  + 884736;            // 294,912 B
    const size_t oWc  = oWp  + 294912;            // 2,654,208 B

    float* P            = (float*)(ws + oP);
    unsigned short* XTb = (unsigned short*)(ws + oXT);
    unsigned short* Yb  = (unsigned short*)(ws + oXT);  // alias (XTb dead after proj epilogue)
    unsigned short* XN  = (unsigned short*)(ws + oXN);
    float* Gp           = (float*)(ws + oXN);               // alias (XN dead after qkv GEMM)
    float* Np           = (float*)(ws + oXN + 11010048);
    unsigned short* XCA = (unsigned short*)(ws + oXN);      // alias (Gp/Np dead after k_sm)
    unsigned short* Qb  = (unsigned short*)(ws + oQ);
    unsigned short* X2p = (unsigned short*)(ws + oQ);   // alias (Qb+Kb dead after k_qk)
    unsigned short* Kb  = (unsigned short*)(ws + oK);
    unsigned short* Vt  = (unsigned short*)(ws + oV);
    unsigned short* ATT = (unsigned short*)(ws + oATT);
    unsigned short* Wq  = (unsigned short*)(ws + oWq);
    unsigned short* Wp  = (unsigned short*)(ws + oWp);
    unsigned short* Wc  = (unsigned short*)(ws + oWc);

    k_prep<<<NN + 256, 256, 0, stream>>>(qkv_w, proj_w, conv_w, pos_w, pos_b, Wq, Wp, Wc, P);
    k_tln<<<BB*98, 256, 0, stream>>>(x, P, ln_g, ln_b, XTb, XN);
    k_gemm<0><<<3528, 256, 0, stream>>>(XN, Wq, qkv_b,
        Qb, Kb, Vt, nullptr, nullptr, nullptr);
    k_qk<<<dim3(7, BH), 256, 0, stream>>>(Qb, Kb, Gp, Np);
    k_sm<<<BH, 256, 0, stream>>>(Gp, Np, temp, rpb, ATT, X2p);
    k_pv<<<dim3(49, BH), 256, 0, stream>>>(ATT, Vt, XCA);
    k_gemm<1><<<1176, 256, 0, stream>>>(XCA, Wp, proj_b,
        nullptr, nullptr, nullptr, XTb, gxca, X2p);
    k_conv<<<1200, 256, 0, stream>>>(X2p, Wc, bn_g, bn_b, bn_mean, bn_var, Yb);
    k_final<<<dim3(56, BB, 2), 256, 0, stream>>>(x, Yb, gamma, out);
}

// Round 10
// 452.910 us; speedup vs baseline: 1.3814x; 1.3814x over previous
//
#include <hip/hip_runtime.h>
#include <hip/hip_bf16.h>
#include <math.h>

#define DIM 384
#define HEADS 6
#define NN 3136
#define BB 16
#define BH (BB*HEADS)
#define HP 58
#define NP (HP*HP)   // 3364 padded image

typedef __attribute__((ext_vector_type(8))) short short8;
typedef __attribute__((ext_vector_type(4))) short short4v;
typedef __attribute__((ext_vector_type(4))) float f32x4;

__device__ __forceinline__ float bf2f(unsigned short u) {
    union { unsigned int i; float f; } v; v.i = ((unsigned int)u) << 16; return v.f;
}
__device__ __forceinline__ unsigned short f2bf(float f) {
    union { float f; unsigned int i; } v; v.f = f;
    unsigned int r = v.i + 0x7fffu + ((v.i >> 16) & 1u);
    return (unsigned short)(r >> 16);
}
__device__ __forceinline__ void glds16(const unsigned short* g, void* l) {
    __builtin_amdgcn_global_load_lds(
        (const __attribute__((address_space(1))) unsigned int*)g,
        (__attribute__((address_space(3))) unsigned int*)l, 16, 0, 0);
}

// ---------------- fused prep: pos table (blocks 0..NN-1) + weight convert ----------------
__global__ void k_prep(const float* __restrict__ qkv_w, const float* __restrict__ proj_w,
                       const float* __restrict__ conv_w,
                       const float* __restrict__ pos_w, const float* __restrict__ pos_b,
                       unsigned short* __restrict__ Wq, unsigned short* __restrict__ Wp,
                       unsigned short* __restrict__ Wc, float* __restrict__ P) {
    int t = threadIdx.x;
    if (blockIdx.x < NN) {
        int n = blockIdx.x; int h = n / 56, w = n % 56;
        __shared__ float feat[64];
        if (t < 64) {
            int axis = t >> 5;      // 0 = y (h), 1 = x (w)
            int k = t & 31; int i = k >> 1;
            float e = (float)((axis ? w : h) + 1) / 56.000001f * 6.28318530717958647692f;
            float arg = e / powf(10000.0f, (float)i / 16.0f);
            feat[t] = (k & 1) ? cosf(arg) : sinf(arg);
        }
        __syncthreads();
        for (int c = t; c < DIM; c += 256) {
            float s = pos_b[c];
            #pragma unroll 8
            for (int k = 0; k < 64; k++) s += feat[k] * pos_w[c*64 + k];
            P[(size_t)n*DIM + c] = s;
        }
    } else {
        int tid = (blockIdx.x - NN) * 256 + t;
        int stride = 256 * 256;
        for (int i = tid; i < 3*DIM*DIM; i += stride) Wq[i] = f2bf(qkv_w[i]);
        for (int i = tid; i < DIM*DIM; i += stride) Wp[i] = f2bf(proj_w[i]);
        for (int i = tid; i < DIM*DIM*9; i += stride) {
            int ii = i % DIM; int rest = i / DIM; int tap = rest % 9; int o = rest / 9;
            Wc[i] = f2bf(conv_w[(size_t)(o*DIM + ii)*9 + tap]);
        }
    }
}

// ---------------- fused transpose + pos add + layernorm ----------------
__global__ __launch_bounds__(256) void k_tln(const float* __restrict__ x, const float* __restrict__ P,
                                             const float* __restrict__ g, const float* __restrict__ be,
                                             unsigned short* __restrict__ XTb, unsigned short* __restrict__ XN) {
    __shared__ float tile[32][388];
    int blk = blockIdx.x;
    int b = blk / 98, nt = blk % 98;
    int n0 = nt*32;
    int t = threadIdx.x;
    #pragma unroll
    for (int it = 0; it < 12; it++) {
        int task = it*256 + t;
        int c = task >> 3, seg = task & 7;
        float4 v = *reinterpret_cast<const float4*>(x + ((size_t)(b*DIM + c))*NN + n0 + seg*4);
        tile[seg*4+0][c] = v.x; tile[seg*4+1][c] = v.y;
        tile[seg*4+2][c] = v.z; tile[seg*4+3][c] = v.w;
    }
    __syncthreads();
    int row = t >> 3, sub = t & 7;
    int n = n0 + row;
    f32x4 xp[12];
    float s = 0.f;
    #pragma unroll
    for (int k = 0; k < 12; k++) {
        int c0 = (k*8 + sub)*4;
        float4 tv = *reinterpret_cast<float4*>(&tile[row][c0]);
        float4 pv = *reinterpret_cast<const float4*>(P + (size_t)n*DIM + c0);
        f32x4 xv = {tv.x+pv.x, tv.y+pv.y, tv.z+pv.z, tv.w+pv.w};
        xp[k] = xv;
        s += xv[0]+xv[1]+xv[2]+xv[3];
        unsigned short pkx[4];
        #pragma unroll
        for (int e=0;e<4;e++) pkx[e] = f2bf(xv[e]);
        *reinterpret_cast<short4v*>(XTb + ((size_t)(b*NN + n))*DIM + c0) = *(short4v*)pkx;
    }
    s += __shfl_xor(s, 1, 64); s += __shfl_xor(s, 2, 64); s += __shfl_xor(s, 4, 64);
    float mean = s * (1.0f/384.0f);
    float sq = 0.f;
    #pragma unroll
    for (int k = 0; k < 12; k++) {
        #pragma unroll
        for (int e = 0; e < 4; e++) { float d = xp[k][e]-mean; sq += d*d; }
    }
    sq += __shfl_xor(sq, 1, 64); sq += __shfl_xor(sq, 2, 64); sq += __shfl_xor(sq, 4, 64);
    float rs = rsqrtf(sq * (1.0f/384.0f) + 1e-6f);
    #pragma unroll
    for (int k = 0; k < 12; k++) {
        int c0 = (k*8 + sub)*4;
        unsigned short pk[4];
        #pragma unroll
        for (int e = 0; e < 4; e++)
            pk[e] = f2bf((xp[k][e]-mean)*rs*g[c0+e] + be[c0+e]);
        *reinterpret_cast<short4v*>(XN + ((size_t)(b*NN + n))*DIM + c0) = *(short4v*)pk;
    }
}

// ---------------- MFMA GEMM (K=384): MODE 0 = qkv, 1 = proj ----------------
// A+B dbuf via swizzled global_load_lds; counted-vmcnt raw barriers (T4) + setprio (T5).
template<int MODE>
__global__ __launch_bounds__(256) void k_gemm(
    const unsigned short* __restrict__ A, const unsigned short* __restrict__ Wt,
    const float* __restrict__ bias,
    unsigned short* __restrict__ Qb, unsigned short* __restrict__ Kb, unsigned short* __restrict__ Vt,
    const unsigned short* __restrict__ XTb, const float* __restrict__ gxca, unsigned short* __restrict__ X2p)
{
    __shared__ __align__(16) char smem[35328];
    auto ctA = (float(*)[69])smem;                     // [128][69] 35328  ([o][m])
    auto ctB = (float(*)[130])smem;                    // [64][130] 33280  ([m][o])

    constexpr int NCT = (MODE == 0) ? 9 : 3;
    constexpr int CPX = (MODE == 0) ? 441 : 147;       // 392*NCT/8
    int bid = blockIdx.x;
    int orig = (bid & 7)*CPX + (bid >> 3);
    int ct = orig % NCT, mt = orig / NCT;
    int m0 = mt*128, o0 = ct*128;
    int t = threadIdx.x;
    int wave = t >> 6, lane = t & 63;
    int wr = wave >> 1, wc = wave & 1;
    int lr = lane & 15, lg = lane >> 4;

    int r0 = t >> 2;
    int swcol = (((t & 3) ^ ((t >> 3) & 3)) << 3);
    const unsigned short* a0 = A  + (size_t)(m0 + r0)*384 + swcol;
    const unsigned short* a1 = A  + (size_t)(m0 + 64 + r0)*384 + swcol;
    const unsigned short* b0 = Wt + (size_t)(o0 + r0)*384 + swcol;
    const unsigned short* b1 = Wt + (size_t)(o0 + 64 + r0)*384 + swcol;
    int rsw = ((lr >> 1) & 3) << 3;    // read-side swizzle (shorts)

    auto stage = [&](char* base, int c) {
        glds16(a0 + c, base + wave*1024);
        glds16(a1 + c, base + 4096 + wave*1024);
        glds16(b0 + c, base + 8192 + wave*1024);
        glds16(b1 + c, base + 12288 + wave*1024);
    };

    f32x4 acc[4][4];
    #pragma unroll
    for (int i=0;i<4;i++) for (int j=0;j<4;j++) acc[i][j] = (f32x4){0.f,0.f,0.f,0.f};

    stage(smem, 0);
    for (int kk = 0; kk < 12; kk++) {
        if (kk < 11) {
            stage(smem + ((kk+1)&1)*16384, (kk+1)*32);
            asm volatile("s_waitcnt vmcnt(4)" ::: "memory");
        } else {
            asm volatile("s_waitcnt vmcnt(0)" ::: "memory");
        }
        __builtin_amdgcn_s_barrier();
        __builtin_amdgcn_sched_barrier(0);
        auto As = (unsigned short(*)[32])(smem + (kk&1)*16384);
        auto Bs = (unsigned short(*)[32])(smem + (kk&1)*16384 + 8192);
        short8 af[4], bfv[4];
        #pragma unroll
        for (int i=0;i<4;i++) af[i]  = *(short8*)&As[wr*64 + i*16 + lr][(lg*8) ^ rsw];
        #pragma unroll
        for (int j=0;j<4;j++) bfv[j] = *(short8*)&Bs[wc*64 + j*16 + lr][(lg*8) ^ rsw];
        __builtin_amdgcn_s_setprio(1);
        #pragma unroll
        for (int i=0;i<4;i++)
            #pragma unroll
            for (int j=0;j<4;j++)
                acc[i][j] = __builtin_amdgcn_mfma_f32_16x16x32_bf16(af[i], bfv[j], acc[i][j], 0, 0, 0);
        __builtin_amdgcn_s_setprio(0);
        __builtin_amdgcn_s_barrier();
        __builtin_amdgcn_sched_barrier(0);
    }

    // ---- epilogue ----
    int comp = (MODE == 0) ? (o0 / DIM) : 0;
    for (int mh = 0; mh < 2; mh++) {
        __syncthreads();
        bool useB = (MODE == 1) || (MODE == 0 && comp == 2);
        if (wr == mh) {
            if (useB) {
                #pragma unroll
                for (int i=0;i<4;i++) for (int j=0;j<4;j++) for (int r=0;r<4;r++)
                    ctB[i*16 + lg*4 + r][wc*64 + j*16 + lr] = acc[i][j][r];
            } else {
                #pragma unroll
                for (int i=0;i<4;i++) for (int j=0;j<4;j++) for (int r=0;r<4;r++)
                    ctA[wc*64 + j*16 + lr][i*16 + lg*4 + r] = acc[i][j][r];
            }
        }
        __syncthreads();
        if (MODE == 1) {
            for (int q = t; q < 1024; q += 256) {   // 64 m-rows x 16 o-segs(8)
                int row = q >> 4, seg = q & 15;
                int m = m0 + mh*64 + row; int b = m/NN; int n = m - b*NN;
                int py = n/56, px = n - py*56;
                int og0 = o0 + seg*8;
                short8 xvb = *(const short8*)(XTb + (size_t)m*DIM + og0);
                unsigned short pk[8];
                #pragma unroll
                for (int e=0;e<8;e++) {
                    float val = ctB[row][seg*8+e] + bias[og0+e];
                    pk[e] = f2bf(bf2f((unsigned short)xvb[e]) + gxca[og0+e]*val);
                }
                *(short8*)(X2p + ((size_t)(b*NP + (py+1)*HP + px + 1))*DIM + og0) = *(short8*)pk;
            }
        } else if (comp < 2) {                      // Q / K: (bh,dd,N) layout
            unsigned short* Dst = (comp == 0) ? Qb : Kb;
            for (int q = t; q < 2048; q += 256) {   // 128 o-rows x 16 m-segs(4)
                int row = q >> 4, seg = q & 15;
                int og = o0 + row; int rem = og - comp*DIM;
                int hh = rem >> 6, dd = rem & 63;
                int m4 = m0 + mh*64 + seg*4; int b = m4/NN; int n = m4 - b*NN;
                float bv = bias[og];
                unsigned short pk[4];
                #pragma unroll
                for (int e=0;e<4;e++) pk[e] = f2bf(ctA[row][seg*4+e] + bv);
                *(short4v*)(Dst + ((size_t)((b*HEADS + hh)*64 + dd))*NN + n) = *(short4v*)pk;
            }
        } else {                                    // V: (bh,N,dd) layout
            for (int q = t; q < 1024; q += 256) {   // 64 m-rows x 16 o-segs(8)
                int row = q >> 4, seg = q & 15;
                int m = m0 + mh*64 + row; int b = m/NN; int n = m - b*NN;
                int og0 = o0 + seg*8; int rem0 = og0 - 2*DIM;
                int hh = rem0 >> 6, dd0 = rem0 & 63;
                unsigned short pk[8];
                #pragma unroll
                for (int e=0;e<8;e++) pk[e] = f2bf(ctB[row][seg*8+e] + bias[og0+e]);
                *(short8*)(Vt + ((size_t)((b*HEADS + hh)*NN + n))*64 + dd0) = *(short8*)pk;
            }
        }
    }
}

// ---------------- conv3x3 + BN + SiLU + residual, counted-vmcnt pipeline (r8) + setprio ----------------
// A-halo DOUBLE buffer (staged at tap 6 of prev kk) + B dbuf in LDS; raw barriers + counted vmcnt.
__global__ __launch_bounds__(256, 3) void k_conv(
    const unsigned short* __restrict__ A, const unsigned short* __restrict__ Wt,
    const float* __restrict__ bn_g, const float* __restrict__ bn_b,
    const float* __restrict__ bn_mean, const float* __restrict__ bn_var,
    unsigned short* __restrict__ Yout)
{
    __shared__ __align__(16) char smem[49152];
    // k-loop: A halo dbuf 2x[256][32] @0 (32KB), B dbuf 2x[128][32] @32768 (16KB)
    auto ctA = (float(*)[69])smem;                     // epilogue alias [64][69] 17664
    auto X2s = (unsigned short(*)[68])(smem + 17664);  // [64][68] 8704

    int bid = blockIdx.x;                 // 1200 = 8*150
    int orig = (bid & 7)*150 + (bid >> 3);
    int ct = orig % 3; int rest = orig / 3;
    int tile = rest % 25; int b = rest / 25;
    int n0 = tile*128, o0 = ct*128;
    int t = threadIdx.x;
    int wave = t >> 6, lane = t & 63;
    int wr = wave >> 1, wc = wave & 1;
    int lr = lane & 15, lg = lane >> 4;
    int qb = n0 + 2*(n0/56);
    const size_t bbase = (size_t)b*NP*DIM;

    int swcol = (((t & 3) ^ ((t >> 3) & 3)) << 3);
    // A-halo: 1024 tasks = 4/thread
    const unsigned short* asrc[4];
    #pragma unroll
    for (int j=0;j<4;j++) {
        int task = j*256 + t;
        int row = task >> 2;
        int q = qb + row; if (q > NP-1) q = NP-1;
        asrc[j] = A + bbase + (size_t)q*DIM + swcol;
    }
    // B: 512 tasks = 2/thread
    const unsigned short* bsrc0 = Wt + (size_t)(o0 + (t>>2))*3456 + swcol;
    const unsigned short* bsrc1 = Wt + (size_t)(o0 + 64 + (t>>2))*3456 + swcol;

    // per-lane MFMA A row offsets (position-relative)
    int qrel[4];
    #pragma unroll
    for (int i=0;i<4;i++) {
        int loc = wr*64 + i*16 + lr;
        int n = n0 + loc; if (n >= NN) n = NN-1;
        qrel[i] = n + 2*(n/56) - qb;
    }

    auto stageA = [&](int bufsel, int c) {
        #pragma unroll
        for (int j=0;j<4;j++) glds16(asrc[j] + c, smem + bufsel*16384 + j*4096 + wave*1024);
    };
    auto stageB = [&](int slot, int off) {
        glds16(bsrc0 + off, smem + 32768 + slot*8192 + wave*1024);
        glds16(bsrc1 + off, smem + 32768 + slot*8192 + 4096 + wave*1024);
    };

    f32x4 acc[4][4];
    #pragma unroll
    for (int i=0;i<4;i++) for (int j=0;j<4;j++) acc[i][j] = (f32x4){0.f,0.f,0.f,0.f};

    stageA(0, 0); stageB(0, 0);
    for (int kk = 0; kk < 12; kk++) {
        auto Ah = (unsigned short(*)[32])(smem + (kk&1)*16384);
        #pragma unroll
        for (int tap = 0; tap < 9; tap++) {
            // issue next-tap B (slot for step s+1)
            if (kk < 11 || tap < 8) {
                int off = (tap < 8) ? ((tap+1)*384 + kk*32) : ((kk+1)*32);
                stageB((kk+tap+1)&1, off);
            }
            if (tap == 6 && kk < 11) stageA((kk+1)&1, (kk+1)*32);
            // counted waits: B(s) must be landed; keep later loads in flight
            if (kk < 11 && (tap == 6 || tap == 7))
                asm volatile("s_waitcnt vmcnt(6)" ::: "memory");
            else if (kk == 11 && tap == 8)
                asm volatile("s_waitcnt vmcnt(0)" ::: "memory");
            else
                asm volatile("s_waitcnt vmcnt(2)" ::: "memory");
            __builtin_amdgcn_s_barrier();
            __builtin_amdgcn_sched_barrier(0);
            auto Bs = (unsigned short(*)[32])(smem + 32768 + ((kk+tap)&1)*8192);
            int toff = (tap/3)*58 + (tap%3);
            short8 af[4], bfv[4];
            #pragma unroll
            for (int j=0;j<4;j++) {
                int brow = wc*64 + j*16 + lr;
                bfv[j] = *(short8*)&Bs[brow][(lg*8) ^ (((brow>>1)&3)<<3)];
            }
            #pragma unroll
            for (int i=0;i<4;i++) {
                int row = qrel[i] + toff;
                af[i] = *(short8*)&Ah[row][(lg*8) ^ (((row>>1)&3)<<3)];
            }
            __builtin_amdgcn_s_setprio(1);
            #pragma unroll
            for (int i=0;i<4;i++)
                #pragma unroll
                for (int j=0;j<4;j++)
                    acc[i][j] = __builtin_amdgcn_mfma_f32_16x16x32_bf16(af[i], bfv[j], acc[i][j], 0, 0, 0);
            __builtin_amdgcn_s_setprio(0);
            __builtin_amdgcn_s_barrier();
            __builtin_amdgcn_sched_barrier(0);
        }
    }

    // ---- epilogue: 4 quadrant passes (mh x oh), coalesced bf16 short8 writes ----
    for (int mh = 0; mh < 2; mh++) {
        for (int oh = 0; oh < 2; oh++) {
            __syncthreads();
            if (wr == mh && wc == oh) {
                #pragma unroll
                for (int i=0;i<4;i++) for (int j=0;j<4;j++) for (int r=0;r<4;r++)
                    ctA[j*16 + lr][i*16 + lg*4 + r] = acc[i][j][r];
            }
            for (int q = t; q < 512; q += 256) {    // residual: 64 m-rows x 8 o-segs(8)
                int row = q >> 3, sg = q & 7;
                int n = n0 + mh*64 + row; int nc = (n < NN) ? n : NN-1;
                int qq = nc + 2*(nc/56) + 59;       // center tap (+1,+1)
                short8 v = *(const short8*)(A + bbase + (size_t)qq*DIM + o0 + oh*64 + sg*8);
                short4v lo = {v[0],v[1],v[2],v[3]}, hi = {v[4],v[5],v[6],v[7]};
                *(short4v*)&X2s[row][sg*8]     = lo;
                *(short4v*)&X2s[row][sg*8 + 4] = hi;
            }
            __syncthreads();
            for (int q = t; q < 512; q += 256) {    // 64 o-rows x 8 n-segs(8)
                int orow = q >> 3, sg = q & 7;
                int o = o0 + oh*64 + orow;
                int n = n0 + mh*64 + sg*8;
                if (n < NN) {
                    float mean = bn_mean[o], rs = rsqrtf(bn_var[o] + 1e-5f);
                    float gg = bn_g[o], bb2 = bn_b[o];
                    unsigned short pk[8];
                    #pragma unroll
                    for (int e=0;e<8;e++) {
                        float xi = (ctA[orow][sg*8+e] - mean)*rs*gg + bb2;
                        float si = xi / (1.0f + __expf(-xi));
                        pk[e] = f2bf(si + bf2f(X2s[sg*8+e][orow]));
                    }
                    *(short8*)(Yout + ((size_t)(b*DIM + o))*NN + n) = *(short8*)pk;
                }
            }
        }
    }
}

// ---------------- attention stage 1: partial G = q k^T + partial sq-norms ----------------
__global__ __launch_bounds__(256) void k_qk(const unsigned short* __restrict__ Qb,
                                            const unsigned short* __restrict__ Kb,
                                            float* __restrict__ Gp, float* __restrict__ Np) {
    int cx = blockIdx.x, bh = blockIdx.y;
    int t = threadIdx.x, wave = t >> 6, lane = t & 63;
    int lr = lane & 15, lg = lane >> 4;
    {   // partial squared norms: 128 rows x 2 threads
        int row = t >> 1, p = t & 1;
        const unsigned short* src = (row < 64)
            ? Qb + ((size_t)bh*64 + row)*NN + cx*448
            : Kb + ((size_t)bh*64 + (row-64))*NN + cx*448;
        float s = 0.f;
        #pragma unroll
        for (int it = 0; it < 28; it++) {
            short8 v = *(const short8*)(src + p*224 + it*8);
            #pragma unroll
            for (int jj=0;jj<8;jj++) { float f = bf2f((unsigned short)v[jj]); s += f*f; }
        }
        s += __shfl_xor(s, 1, 64);
        if (p == 0) Np[((size_t)bh*7 + cx)*128 + row] = s;
    }
    f32x4 acc[4];
    #pragma unroll
    for (int j=0;j<4;j++) acc[j] = (f32x4){0.f,0.f,0.f,0.f};
    const unsigned short* qrow = Qb + ((size_t)bh*64 + wave*16 + lr)*NN + cx*448;
    const unsigned short* kbase = Kb + (size_t)bh*64*NN + cx*448;
    for (int ks = 0; ks < 14; ks++) {
        short8 a = *(const short8*)(qrow + ks*32 + lg*8);
        #pragma unroll
        for (int j=0;j<4;j++) {
            short8 bfr = *(const short8*)(kbase + (size_t)(j*16+lr)*NN + ks*32 + lg*8);
            acc[j] = __builtin_amdgcn_mfma_f32_16x16x32_bf16(a, bfr, acc[j], 0, 0, 0);
        }
    }
    float* gbase = Gp + ((size_t)bh*7 + cx)*4096;
    #pragma unroll
    for (int j=0;j<4;j++)
        #pragma unroll
        for (int r=0;r<4;r++)
            gbase[(wave*16 + lg*4 + r)*64 + j*16 + lr] = acc[j][r];
}

// ---------------- attention stage 2: combine + softmax -> ATT; + X2p pad-ring zero ----------------
__global__ __launch_bounds__(256) void k_sm(const float* __restrict__ Gp, const float* __restrict__ Np,
                                            const float* __restrict__ temperature,
                                            const float* __restrict__ rpb,
                                            unsigned short* __restrict__ ATT,
                                            unsigned short* __restrict__ X2p) {
    int bh = blockIdx.x; int h = bh % HEADS;
    int t = threadIdx.x;
    __shared__ float snorm[128];
    if (t < 128) {
        float s = 0.f;
        #pragma unroll
        for (int cx=0;cx<7;cx++) s += Np[((size_t)bh*7 + cx)*128 + t];
        snorm[t] = fmaxf(sqrtf(s), 1e-12f);
    }
    __syncthreads();
    int dq = t >> 2, de0 = (t & 3) * 16;
    f32x4 g[4];
    #pragma unroll
    for (int i=0;i<4;i++) g[i] = (f32x4){0.f,0.f,0.f,0.f};
    #pragma unroll
    for (int cx=0;cx<7;cx++) {
        const float* base = Gp + ((size_t)bh*7 + cx)*4096 + dq*64 + de0;
        #pragma unroll
        for (int i=0;i<4;i++) {
            float4 v = *(const float4*)(base + i*4);
            g[i][0]+=v.x; g[i][1]+=v.y; g[i][2]+=v.z; g[i][3]+=v.w;
        }
    }
    float temp = temperature[h];
    float bias = rpb[HEADS + h];
    float qn = snorm[dq];
    float lv[16]; float mx = -1e30f;
    #pragma unroll
    for (int i=0;i<4;i++)
        #pragma unroll
        for (int e=0;e<4;e++) {
            int de = de0 + i*4 + e;
            float v = g[i][e] / (qn * snorm[64 + de]) * temp + bias;
            lv[i*4+e] = v; mx = fmaxf(mx, v);
        }
    mx = fmaxf(mx, __shfl_xor(mx, 1, 64));
    mx = fmaxf(mx, __shfl_xor(mx, 2, 64));
    float se = 0.f;
    #pragma unroll
    for (int e=0;e<16;e++) { lv[e] = __expf(lv[e]-mx); se += lv[e]; }
    se += __shfl_xor(se, 1, 64);
    se += __shfl_xor(se, 2, 64);
    float inv = 1.0f/se;
    unsigned short pk[16];
    #pragma unroll
    for (int e=0;e<16;e++) pk[e] = f2bf(lv[e]*inv);
    unsigned short* dst = ATT + ((size_t)bh*64 + dq)*64 + de0;
    *(short8*)dst       = *(short8*)pk;
    *(short8*)(dst + 8) = *(short8*)(pk + 8);

    // ---- X2p pad-ring zero (Q/K dead after k_qk; 96 blocks = 16 b x 6 parts) ----
    int pb = bh / 6, part = bh % 6;
    unsigned short* base2 = X2p + (size_t)pb*NP*DIM;
    short8 z = {0,0,0,0,0,0,0,0};
    for (int task = part*256 + t; task < 10944; task += 1536) {
        int pos = task / 48, seg = task - pos*48;
        int py, px;
        if (pos < 58)       { py = 0;  px = pos; }
        else if (pos < 116) { py = 57; px = pos - 58; }
        else if (pos < 172) { py = pos - 115; px = 0; }
        else                { py = pos - 171; px = 57; }
        *(short8*)(base2 + ((size_t)(py*HP + px))*DIM + seg*8) = z;
    }
}

// ---------------- PV: XCA[b][n][h*64+dd] = sum_e ATT[dd][e] * V[e][n] ----------------
__global__ __launch_bounds__(256) void k_pv(const unsigned short* __restrict__ ATT,
                                            const unsigned short* __restrict__ Vt,
                                            unsigned short* __restrict__ XCA) {
    int nt = blockIdx.x, bh = blockIdx.y;
    int b = bh / HEADS, h = bh % HEADS;
    int t = threadIdx.x, wave = t >> 6, lane = t & 63;
    int lr = lane & 15, lg = lane >> 4;
    int n0 = nt*64;
    __shared__ float ctP[64][67];
    f32x4 acc[4];
    for (int i=0;i<4;i++) acc[i] = (f32x4){0.f,0.f,0.f,0.f};
    for (int ks=0; ks<2; ks++) {
        short8 bfr = *reinterpret_cast<const short8*>(Vt + ((size_t)bh*NN + n0 + wave*16 + lr)*64 + ks*32 + lg*8);
        for (int i=0;i<4;i++) {
            short8 a = *reinterpret_cast<const short8*>(ATT + ((size_t)bh*64 + i*16 + lr)*64 + ks*32 + lg*8);
            acc[i] = __builtin_amdgcn_mfma_f32_16x16x32_bf16(a, bfr, acc[i], 0, 0, 0);
        }
    }
    int nl = wave*16 + lr;
    #pragma unroll
    for (int i=0;i<4;i++)
        #pragma unroll
        for (int r=0;r<4;r++) ctP[nl][i*16 + lg*4 + r] = acc[i][r];
    __syncthreads();
    for (int q = t; q < 512; q += 256) {   // 64 n-rows x 8 dd-segs(8)
        int row = q >> 3, seg = q & 7;
        unsigned short pk[8];
        #pragma unroll
        for (int e=0;e<8;e++) pk[e] = f2bf(ctP[row][seg*8+e]);
        *(short8*)(XCA + ((size_t)(b*NN + n0 + row))*DIM + h*64 + seg*8) = *(short8*)pk;
    }
}

// ---------------- final: out = x + gamma-shuffled residual (Y bf16) ----------------
__global__ __launch_bounds__(256) void k_final(const float* __restrict__ x, const unsigned short* __restrict__ Yb,
                                               const float* __restrict__ gamma, float* __restrict__ out) {
    int i = blockIdx.x, b = blockIdx.y, kc = blockIdx.z;
    __shared__ float tile[56*193];
    int t = threadIdx.x;
    int k0 = kc*192;
    const unsigned short* ybase = Yb + (size_t)b*DIM*NN + (size_t)i*21504 + k0;
    for (int q = t; q < 56*24; q += 256) {
        int j = q / 24, c8 = (q % 24) * 8;
        short8 v = *(const short8*)(ybase + (size_t)j*384 + c8);
        float* dst = &tile[j*193 + c8];
        #pragma unroll
        for (int e=0;e<8;e++) dst[e] = bf2f((unsigned short)v[e]);
    }
    __syncthreads();
    for (int q = t; q < 192*56; q += 256) {
        int kl = q / 56, j = q % 56;
        int k = k0 + kl;
        size_t gi = ((size_t)(b*DIM + k))*NN + (size_t)i*56 + j;
        out[gi] = x[gi] + gamma[k] * tile[j*193 + kl];
    }
}

extern "C" void kernel_launch(void* const* d_in, const int* in_sizes, int n_in,
                              void* d_out, int out_size, void* d_ws, size_t ws_size,
                              hipStream_t stream) {
    const float* x       = (const float*)d_in[0];
    const float* pos_w   = (const float*)d_in[1];
    const float* pos_b   = (const float*)d_in[2];
    const float* ln_g    = (const float*)d_in[3];
    const float* ln_b    = (const float*)d_in[4];
    const float* gxca    = (const float*)d_in[5];
    const float* temp    = (const float*)d_in[6];
    const float* qkv_w   = (const float*)d_in[7];
    const float* qkv_b   = (const float*)d_in[8];
    const float* proj_w  = (const float*)d_in[9];
    const float* proj_b  = (const float*)d_in[10];
    const float* rpb     = (const float*)d_in[11];
    const float* conv_w  = (const float*)d_in[12];
    const float* bn_g    = (const float*)d_in[13];
    const float* bn_b    = (const float*)d_in[14];
    const float* bn_mean = (const float*)d_in[15];
    const float* bn_var  = (const float*)d_in[16];
    const float* gamma   = (const float*)d_in[17];
    float* out = (float*)d_out;
    char* ws = (char*)d_ws;

    const size_t oP   = 0;                        // P: 4,816,896 B
    const size_t oXT  = oP   + 4816896;           // XTb bf16 38.5MB (reused as Y bf16 after proj)
    const size_t oXN  = oXT  + 77070336;          // XN bf16: 38,535,168 B   (reused as Gp/Np, then XCA)
    const size_t oQ   = oXN  + 38535168;          // Qb bf16                  (reused as X2p padded, spans into Kb)
    const size_t oK   = oQ   + 38535168;          // Kb bf16
    const size_t oV   = oK   + 38535168;          // Vt bf16
    const size_t oATT = oV   + 38535168;          // ATT bf16: 786,432 B
    const size_t oWq  = oATT + 786432;            // 884,736 B
    const size_t oWp  = oWq  + 884736;            // 294,912 B
    const size_t oWc  = oWp  + 294912;            // 2,654,208 B

    float* P            = (float*)(ws + oP);
    unsigned short* XTb = (unsigned short*)(ws + oXT);
    unsigned short* Yb  = (unsigned short*)(ws + oXT);  // alias (XTb dead after proj epilogue)
    unsigned short* XN  = (unsigned short*)(ws + oXN);
    float* Gp           = (float*)(ws + oXN);               // alias (XN dead after qkv GEMM)
    float* Np           = (float*)(ws + oXN + 11010048);
    unsigned short* XCA = (unsigned short*)(ws + oXN);      // alias (Gp/Np dead after k_sm)
    unsigned short* Qb  = (unsigned short*)(ws + oQ);
    unsigned short* X2p = (unsigned short*)(ws + oQ);   // alias (Qb+Kb dead after k_qk)
    unsigned short* Kb  = (unsigned short*)(ws + oK);
    unsigned short* Vt  = (unsigned short*)(ws + oV);
    unsigned short* ATT = (unsigned short*)(ws + oATT);
    unsigned short* Wq  = (unsigned short*)(ws + oWq);
    unsigned short* Wp  = (unsigned short*)(ws + oWp);
    unsigned short* Wc  = (unsigned short*)(ws + oWc);

    k_prep<<<NN + 256, 256, 0, stream>>>(qkv_w, proj_w, conv_w, pos_w, pos_b, Wq, Wp, Wc, P);
    k_tln<<<BB*98, 256, 0, stream>>>(x, P, ln_g, ln_b, XTb, XN);
    k_gemm<0><<<3528, 256, 0, stream>>>(XN, Wq, qkv_b,
        Qb, Kb, Vt, nullptr, nullptr, nullptr);
    k_qk<<<dim3(7, BH), 256, 0, stream>>>(Qb, Kb, Gp, Np);
    k_sm<<<BH, 256, 0, stream>>>(Gp, Np, temp, rpb, ATT, X2p);
    k_pv<<<dim3(49, BH), 256, 0, stream>>>(ATT, Vt, XCA);
    k_gemm<1><<<1176, 256, 0, stream>>>(XCA, Wp, proj_b,
        nullptr, nullptr, nullptr, XTb, gxca, X2p);
    k_conv<<<1200, 256, 0, stream>>>(X2p, Wc, bn_g, bn_b, bn_mean, bn_var, Yb);
    k_final<<<dim3(56, BB, 2), 256, 0, stream>>>(x, Yb, gamma, out);
}

// Round 11
// 439.809 us; speedup vs baseline: 1.4225x; 1.0298x over previous
//
#include <hip/hip_runtime.h>
#include <hip/hip_bf16.h>
#include <math.h>

#define DIM 384
#define HEADS 6
#define NN 3136
#define BB 16
#define BH (BB*HEADS)
#define HP 58
#define NP (HP*HP)   // 3364 padded image

typedef __attribute__((ext_vector_type(8))) short short8;
typedef __attribute__((ext_vector_type(4))) short short4v;
typedef __attribute__((ext_vector_type(4))) float f32x4;

__device__ __forceinline__ float bf2f(unsigned short u) {
    union { unsigned int i; float f; } v; v.i = ((unsigned int)u) << 16; return v.f;
}
__device__ __forceinline__ unsigned short f2bf(float f) {
    union { float f; unsigned int i; } v; v.f = f;
    unsigned int r = v.i + 0x7fffu + ((v.i >> 16) & 1u);
    return (unsigned short)(r >> 16);
}
__device__ __forceinline__ void glds16(const unsigned short* g, void* l) {
    __builtin_amdgcn_global_load_lds(
        (const __attribute__((address_space(1))) unsigned int*)g,
        (__attribute__((address_space(3))) unsigned int*)l, 16, 0, 0);
}

// ---------------- fused prep: pos table (blocks 0..NN-1) + weight convert ----------------
__global__ void k_prep(const float* __restrict__ qkv_w, const float* __restrict__ proj_w,
                       const float* __restrict__ conv_w,
                       const float* __restrict__ pos_w, const float* __restrict__ pos_b,
                       unsigned short* __restrict__ Wq, unsigned short* __restrict__ Wp,
                       unsigned short* __restrict__ Wc, float* __restrict__ P) {
    int t = threadIdx.x;
    if (blockIdx.x < NN) {
        int n = blockIdx.x; int h = n / 56, w = n % 56;
        __shared__ float feat[64];
        if (t < 64) {
            int axis = t >> 5;      // 0 = y (h), 1 = x (w)
            int k = t & 31; int i = k >> 1;
            float e = (float)((axis ? w : h) + 1) / 56.000001f * 6.28318530717958647692f;
            float arg = e / powf(10000.0f, (float)i / 16.0f);
            feat[t] = (k & 1) ? cosf(arg) : sinf(arg);
        }
        __syncthreads();
        for (int c = t; c < DIM; c += 256) {
            float s = pos_b[c];
            #pragma unroll 8
            for (int k = 0; k < 64; k++) s += feat[k] * pos_w[c*64 + k];
            P[(size_t)n*DIM + c] = s;
        }
    } else {
        int tid = (blockIdx.x - NN) * 256 + t;
        int stride = 256 * 256;
        for (int i = tid; i < 3*DIM*DIM; i += stride) Wq[i] = f2bf(qkv_w[i]);
        for (int i = tid; i < DIM*DIM; i += stride) Wp[i] = f2bf(proj_w[i]);
        for (int i = tid; i < DIM*DIM*9; i += stride) {
            int ii = i % DIM; int rest = i / DIM; int tap = rest % 9; int o = rest / 9;
            Wc[i] = f2bf(conv_w[(size_t)(o*DIM + ii)*9 + tap]);
        }
    }
}

// ---------------- fused transpose + pos add + layernorm ----------------
__global__ __launch_bounds__(256) void k_tln(const float* __restrict__ x, const float* __restrict__ P,
                                             const float* __restrict__ g, const float* __restrict__ be,
                                             unsigned short* __restrict__ XTb, unsigned short* __restrict__ XN) {
    __shared__ float tile[32][388];
    int blk = blockIdx.x;
    int b = blk / 98, nt = blk % 98;
    int n0 = nt*32;
    int t = threadIdx.x;
    #pragma unroll
    for (int it = 0; it < 12; it++) {
        int task = it*256 + t;
        int c = task >> 3, seg = task & 7;
        float4 v = *reinterpret_cast<const float4*>(x + ((size_t)(b*DIM + c))*NN + n0 + seg*4);
        tile[seg*4+0][c] = v.x; tile[seg*4+1][c] = v.y;
        tile[seg*4+2][c] = v.z; tile[seg*4+3][c] = v.w;
    }
    __syncthreads();
    int row = t >> 3, sub = t & 7;
    int n = n0 + row;
    f32x4 xp[12];
    float s = 0.f;
    #pragma unroll
    for (int k = 0; k < 12; k++) {
        int c0 = (k*8 + sub)*4;
        float4 tv = *reinterpret_cast<float4*>(&tile[row][c0]);
        float4 pv = *reinterpret_cast<const float4*>(P + (size_t)n*DIM + c0);
        f32x4 xv = {tv.x+pv.x, tv.y+pv.y, tv.z+pv.z, tv.w+pv.w};
        xp[k] = xv;
        s += xv[0]+xv[1]+xv[2]+xv[3];
        unsigned short pkx[4];
        #pragma unroll
        for (int e=0;e<4;e++) pkx[e] = f2bf(xv[e]);
        *reinterpret_cast<short4v*>(XTb + ((size_t)(b*NN + n))*DIM + c0) = *(short4v*)pkx;
    }
    s += __shfl_xor(s, 1, 64); s += __shfl_xor(s, 2, 64); s += __shfl_xor(s, 4, 64);
    float mean = s * (1.0f/384.0f);
    float sq = 0.f;
    #pragma unroll
    for (int k = 0; k < 12; k++) {
        #pragma unroll
        for (int e = 0; e < 4; e++) { float d = xp[k][e]-mean; sq += d*d; }
    }
    sq += __shfl_xor(sq, 1, 64); sq += __shfl_xor(sq, 2, 64); sq += __shfl_xor(sq, 4, 64);
    float rs = rsqrtf(sq * (1.0f/384.0f) + 1e-6f);
    #pragma unroll
    for (int k = 0; k < 12; k++) {
        int c0 = (k*8 + sub)*4;
        unsigned short pk[4];
        #pragma unroll
        for (int e = 0; e < 4; e++)
            pk[e] = f2bf((xp[k][e]-mean)*rs*g[c0+e] + be[c0+e]);
        *reinterpret_cast<short4v*>(XN + ((size_t)(b*NN + n))*DIM + c0) = *(short4v*)pk;
    }
}

// ---------------- MFMA GEMM (K=384): MODE 0 = qkv, 1 = proj ----------------
// A+B dbuf via swizzled global_load_lds; counted-vmcnt raw barriers (T4) + setprio (T5).
template<int MODE>
__global__ __launch_bounds__(256) void k_gemm(
    const unsigned short* __restrict__ A, const unsigned short* __restrict__ Wt,
    const float* __restrict__ bias,
    unsigned short* __restrict__ Qb, unsigned short* __restrict__ Kb, unsigned short* __restrict__ Vt,
    const unsigned short* __restrict__ XTb, const float* __restrict__ gxca, unsigned short* __restrict__ X2p)
{
    __shared__ __align__(16) char smem[35328];
    auto ctA = (float(*)[69])smem;                     // [128][69] 35328  ([o][m])
    auto ctB = (float(*)[130])smem;                    // [64][130] 33280  ([m][o])

    constexpr int NCT = (MODE == 0) ? 9 : 3;
    constexpr int CPX = (MODE == 0) ? 441 : 147;       // 392*NCT/8
    int bid = blockIdx.x;
    int orig = (bid & 7)*CPX + (bid >> 3);
    int ct = orig % NCT, mt = orig / NCT;
    int m0 = mt*128, o0 = ct*128;
    int t = threadIdx.x;
    int wave = t >> 6, lane = t & 63;
    int wr = wave >> 1, wc = wave & 1;
    int lr = lane & 15, lg = lane >> 4;

    int r0 = t >> 2;
    int swcol = (((t & 3) ^ ((t >> 3) & 3)) << 3);
    const unsigned short* a0 = A  + (size_t)(m0 + r0)*384 + swcol;
    const unsigned short* a1 = A  + (size_t)(m0 + 64 + r0)*384 + swcol;
    const unsigned short* b0 = Wt + (size_t)(o0 + r0)*384 + swcol;
    const unsigned short* b1 = Wt + (size_t)(o0 + 64 + r0)*384 + swcol;
    int rsw = ((lr >> 1) & 3) << 3;    // read-side swizzle (shorts)

    auto stage = [&](char* base, int c) {
        glds16(a0 + c, base + wave*1024);
        glds16(a1 + c, base + 4096 + wave*1024);
        glds16(b0 + c, base + 8192 + wave*1024);
        glds16(b1 + c, base + 12288 + wave*1024);
    };

    f32x4 acc[4][4];
    #pragma unroll
    for (int i=0;i<4;i++) for (int j=0;j<4;j++) acc[i][j] = (f32x4){0.f,0.f,0.f,0.f};

    stage(smem, 0);
    for (int kk = 0; kk < 12; kk++) {
        if (kk < 11) {
            stage(smem + ((kk+1)&1)*16384, (kk+1)*32);
            asm volatile("s_waitcnt vmcnt(4)" ::: "memory");
        } else {
            asm volatile("s_waitcnt vmcnt(0)" ::: "memory");
        }
        __builtin_amdgcn_s_barrier();
        __builtin_amdgcn_sched_barrier(0);
        auto As = (unsigned short(*)[32])(smem + (kk&1)*16384);
        auto Bs = (unsigned short(*)[32])(smem + (kk&1)*16384 + 8192);
        short8 af[4], bfv[4];
        #pragma unroll
        for (int i=0;i<4;i++) af[i]  = *(short8*)&As[wr*64 + i*16 + lr][(lg*8) ^ rsw];
        #pragma unroll
        for (int j=0;j<4;j++) bfv[j] = *(short8*)&Bs[wc*64 + j*16 + lr][(lg*8) ^ rsw];
        __builtin_amdgcn_s_setprio(1);
        #pragma unroll
        for (int i=0;i<4;i++)
            #pragma unroll
            for (int j=0;j<4;j++)
                acc[i][j] = __builtin_amdgcn_mfma_f32_16x16x32_bf16(af[i], bfv[j], acc[i][j], 0, 0, 0);
        __builtin_amdgcn_s_setprio(0);
        __builtin_amdgcn_s_barrier();
        __builtin_amdgcn_sched_barrier(0);
    }

    // ---- epilogue ----
    int comp = (MODE == 0) ? (o0 / DIM) : 0;
    for (int mh = 0; mh < 2; mh++) {
        __syncthreads();
        bool useB = (MODE == 1) || (MODE == 0 && comp == 2);
        if (wr == mh) {
            if (useB) {
                #pragma unroll
                for (int i=0;i<4;i++) for (int j=0;j<4;j++) for (int r=0;r<4;r++)
                    ctB[i*16 + lg*4 + r][wc*64 + j*16 + lr] = acc[i][j][r];
            } else {
                #pragma unroll
                for (int i=0;i<4;i++) for (int j=0;j<4;j++) for (int r=0;r<4;r++)
                    ctA[wc*64 + j*16 + lr][i*16 + lg*4 + r] = acc[i][j][r];
            }
        }
        __syncthreads();
        if (MODE == 1) {
            for (int q = t; q < 1024; q += 256) {   // 64 m-rows x 16 o-segs(8)
                int row = q >> 4, seg = q & 15;
                int m = m0 + mh*64 + row; int b = m/NN; int n = m - b*NN;
                int py = n/56, px = n - py*56;
                int og0 = o0 + seg*8;
                short8 xvb = *(const short8*)(XTb + (size_t)m*DIM + og0);
                unsigned short pk[8];
                #pragma unroll
                for (int e=0;e<8;e++) {
                    float val = ctB[row][seg*8+e] + bias[og0+e];
                    pk[e] = f2bf(bf2f((unsigned short)xvb[e]) + gxca[og0+e]*val);
                }
                *(short8*)(X2p + ((size_t)(b*NP + (py+1)*HP + px + 1))*DIM + og0) = *(short8*)pk;
            }
        } else if (comp < 2) {                      // Q / K: (bh,dd,N) layout
            unsigned short* Dst = (comp == 0) ? Qb : Kb;
            for (int q = t; q < 2048; q += 256) {   // 128 o-rows x 16 m-segs(4)
                int row = q >> 4, seg = q & 15;
                int og = o0 + row; int rem = og - comp*DIM;
                int hh = rem >> 6, dd = rem & 63;
                int m4 = m0 + mh*64 + seg*4; int b = m4/NN; int n = m4 - b*NN;
                float bv = bias[og];
                unsigned short pk[4];
                #pragma unroll
                for (int e=0;e<4;e++) pk[e] = f2bf(ctA[row][seg*4+e] + bv);
                *(short4v*)(Dst + ((size_t)((b*HEADS + hh)*64 + dd))*NN + n) = *(short4v*)pk;
            }
        } else {                                    // V: (bh,N,dd) layout
            for (int q = t; q < 1024; q += 256) {   // 64 m-rows x 16 o-segs(8)
                int row = q >> 4, seg = q & 15;
                int m = m0 + mh*64 + row; int b = m/NN; int n = m - b*NN;
                int og0 = o0 + seg*8; int rem0 = og0 - 2*DIM;
                int hh = rem0 >> 6, dd0 = rem0 & 63;
                unsigned short pk[8];
                #pragma unroll
                for (int e=0;e<8;e++) pk[e] = f2bf(ctB[row][seg*8+e] + bias[og0+e]);
                *(short8*)(Vt + ((size_t)((b*HEADS + hh)*NN + n))*64 + dd0) = *(short8*)pk;
            }
        }
    }
}

// ---------------- conv3x3 + BN + SiLU + residual, counted-vmcnt pipeline + setprio ----------------
__global__ __launch_bounds__(256, 3) void k_conv(
    const unsigned short* __restrict__ A, const unsigned short* __restrict__ Wt,
    const float* __restrict__ bn_g, const float* __restrict__ bn_b,
    const float* __restrict__ bn_mean, const float* __restrict__ bn_var,
    unsigned short* __restrict__ Yout)
{
    __shared__ __align__(16) char smem[49152];
    // k-loop: A halo dbuf 2x[256][32] @0 (32KB), B dbuf 2x[128][32] @32768 (16KB)
    auto ctA = (float(*)[69])smem;                     // epilogue alias [64][69] 17664
    auto X2s = (unsigned short(*)[68])(smem + 17664);  // [64][68] 8704

    int bid = blockIdx.x;                 // 1200 = 8*150
    int orig = (bid & 7)*150 + (bid >> 3);
    int ct = orig % 3; int rest = orig / 3;
    int tile = rest % 25; int b = rest / 25;
    int n0 = tile*128, o0 = ct*128;
    int t = threadIdx.x;
    int wave = t >> 6, lane = t & 63;
    int wr = wave >> 1, wc = wave & 1;
    int lr = lane & 15, lg = lane >> 4;
    int qb = n0 + 2*(n0/56);
    const size_t bbase = (size_t)b*NP*DIM;

    int swcol = (((t & 3) ^ ((t >> 3) & 3)) << 3);
    const unsigned short* asrc[4];
    #pragma unroll
    for (int j=0;j<4;j++) {
        int task = j*256 + t;
        int row = task >> 2;
        int q = qb + row; if (q > NP-1) q = NP-1;
        asrc[j] = A + bbase + (size_t)q*DIM + swcol;
    }
    const unsigned short* bsrc0 = Wt + (size_t)(o0 + (t>>2))*3456 + swcol;
    const unsigned short* bsrc1 = Wt + (size_t)(o0 + 64 + (t>>2))*3456 + swcol;

    int qrel[4];
    #pragma unroll
    for (int i=0;i<4;i++) {
        int loc = wr*64 + i*16 + lr;
        int n = n0 + loc; if (n >= NN) n = NN-1;
        qrel[i] = n + 2*(n/56) - qb;
    }

    auto stageA = [&](int bufsel, int c) {
        #pragma unroll
        for (int j=0;j<4;j++) glds16(asrc[j] + c, smem + bufsel*16384 + j*4096 + wave*1024);
    };
    auto stageB = [&](int slot, int off) {
        glds16(bsrc0 + off, smem + 32768 + slot*8192 + wave*1024);
        glds16(bsrc1 + off, smem + 32768 + slot*8192 + 4096 + wave*1024);
    };

    f32x4 acc[4][4];
    #pragma unroll
    for (int i=0;i<4;i++) for (int j=0;j<4;j++) acc[i][j] = (f32x4){0.f,0.f,0.f,0.f};

    stageA(0, 0); stageB(0, 0);
    for (int kk = 0; kk < 12; kk++) {
        auto Ah = (unsigned short(*)[32])(smem + (kk&1)*16384);
        #pragma unroll
        for (int tap = 0; tap < 9; tap++) {
            if (kk < 11 || tap < 8) {
                int off = (tap < 8) ? ((tap+1)*384 + kk*32) : ((kk+1)*32);
                stageB((kk+tap+1)&1, off);
            }
            if (tap == 6 && kk < 11) stageA((kk+1)&1, (kk+1)*32);
            if (kk < 11 && (tap == 6 || tap == 7))
                asm volatile("s_waitcnt vmcnt(6)" ::: "memory");
            else if (kk == 11 && tap == 8)
                asm volatile("s_waitcnt vmcnt(0)" ::: "memory");
            else
                asm volatile("s_waitcnt vmcnt(2)" ::: "memory");
            __builtin_amdgcn_s_barrier();
            __builtin_amdgcn_sched_barrier(0);
            auto Bs = (unsigned short(*)[32])(smem + 32768 + ((kk+tap)&1)*8192);
            int toff = (tap/3)*58 + (tap%3);
            short8 af[4], bfv[4];
            #pragma unroll
            for (int j=0;j<4;j++) {
                int brow = wc*64 + j*16 + lr;
                bfv[j] = *(short8*)&Bs[brow][(lg*8) ^ (((brow>>1)&3)<<3)];
            }
            #pragma unroll
            for (int i=0;i<4;i++) {
                int row = qrel[i] + toff;
                af[i] = *(short8*)&Ah[row][(lg*8) ^ (((row>>1)&3)<<3)];
            }
            __builtin_amdgcn_s_setprio(1);
            #pragma unroll
            for (int i=0;i<4;i++)
                #pragma unroll
                for (int j=0;j<4;j++)
                    acc[i][j] = __builtin_amdgcn_mfma_f32_16x16x32_bf16(af[i], bfv[j], acc[i][j], 0, 0, 0);
            __builtin_amdgcn_s_setprio(0);
            __builtin_amdgcn_s_barrier();
            __builtin_amdgcn_sched_barrier(0);
        }
    }

    // ---- epilogue: 4 quadrant passes (mh x oh), coalesced bf16 short8 writes ----
    for (int mh = 0; mh < 2; mh++) {
        for (int oh = 0; oh < 2; oh++) {
            __syncthreads();
            if (wr == mh && wc == oh) {
                #pragma unroll
                for (int i=0;i<4;i++) for (int j=0;j<4;j++) for (int r=0;r<4;r++)
                    ctA[j*16 + lr][i*16 + lg*4 + r] = acc[i][j][r];
            }
            for (int q = t; q < 512; q += 256) {    // residual: 64 m-rows x 8 o-segs(8)
                int row = q >> 3, sg = q & 7;
                int n = n0 + mh*64 + row; int nc = (n < NN) ? n : NN-1;
                int qq = nc + 2*(nc/56) + 59;       // center tap (+1,+1)
                short8 v = *(const short8*)(A + bbase + (size_t)qq*DIM + o0 + oh*64 + sg*8);
                short4v lo = {v[0],v[1],v[2],v[3]}, hi = {v[4],v[5],v[6],v[7]};
                *(short4v*)&X2s[row][sg*8]     = lo;
                *(short4v*)&X2s[row][sg*8 + 4] = hi;
            }
            __syncthreads();
            for (int q = t; q < 512; q += 256) {    // 64 o-rows x 8 n-segs(8)
                int orow = q >> 3, sg = q & 7;
                int o = o0 + oh*64 + orow;
                int n = n0 + mh*64 + sg*8;
                if (n < NN) {
                    float mean = bn_mean[o], rs = rsqrtf(bn_var[o] + 1e-5f);
                    float gg = bn_g[o], bb2 = bn_b[o];
                    unsigned short pk[8];
                    #pragma unroll
                    for (int e=0;e<8;e++) {
                        float xi = (ctA[orow][sg*8+e] - mean)*rs*gg + bb2;
                        float si = xi / (1.0f + __expf(-xi));
                        pk[e] = f2bf(si + bf2f(X2s[sg*8+e][orow]));
                    }
                    *(short8*)(Yout + ((size_t)(b*DIM + o))*NN + n) = *(short8*)pk;
                }
            }
        }
    }
}

// ---------------- attention stage 1: partial G = q k^T (bf16 out) + FUSED sq-norms ----------------
// Norms computed from the SAME fragments the MFMA consumes — no separate 77MB pass.
__global__ __launch_bounds__(256) void k_qk(const unsigned short* __restrict__ Qb,
                                            const unsigned short* __restrict__ Kb,
                                            unsigned short* __restrict__ Gp, float* __restrict__ Np) {
    int cx = blockIdx.x, bh = blockIdx.y;
    int t = threadIdx.x, wave = t >> 6, lane = t & 63;
    int lr = lane & 15, lg = lane >> 4;
    f32x4 acc[4];
    #pragma unroll
    for (int j=0;j<4;j++) acc[j] = (f32x4){0.f,0.f,0.f,0.f};
    float sq = 0.f;
    float sk0 = 0.f, sk1 = 0.f, sk2 = 0.f, sk3 = 0.f;
    const unsigned short* qrow = Qb + ((size_t)bh*64 + wave*16 + lr)*NN + cx*448;
    const unsigned short* kbase = Kb + (size_t)bh*64*NN + cx*448;
    for (int ks = 0; ks < 14; ks++) {
        short8 a = *(const short8*)(qrow + ks*32 + lg*8);
        #pragma unroll
        for (int e=0;e<8;e++) { float f = bf2f((unsigned short)a[e]); sq += f*f; }
        #pragma unroll
        for (int j=0;j<4;j++) {
            short8 bfr = *(const short8*)(kbase + (size_t)(j*16+lr)*NN + ks*32 + lg*8);
            float* skp = (j==0)?&sk0:(j==1)?&sk1:(j==2)?&sk2:&sk3;
            float sloc = 0.f;
            #pragma unroll
            for (int e=0;e<8;e++) { float f = bf2f((unsigned short)bfr[e]); sloc += f*f; }
            *skp += sloc;
            acc[j] = __builtin_amdgcn_mfma_f32_16x16x32_bf16(a, bfr, acc[j], 0, 0, 0);
        }
    }
    // reduce over lg groups (lanes lr, lr+16, lr+32, lr+48)
    sq  += __shfl_xor(sq, 16, 64);  sq  += __shfl_xor(sq, 32, 64);
    sk0 += __shfl_xor(sk0, 16, 64); sk0 += __shfl_xor(sk0, 32, 64);
    sk1 += __shfl_xor(sk1, 16, 64); sk1 += __shfl_xor(sk1, 32, 64);
    sk2 += __shfl_xor(sk2, 16, 64); sk2 += __shfl_xor(sk2, 32, 64);
    sk3 += __shfl_xor(sk3, 16, 64); sk3 += __shfl_xor(sk3, 32, 64);
    float* npb = Np + ((size_t)bh*7 + cx)*128;
    if (lane < 16) {
        npb[wave*16 + lane] = sq;            // q rows (each wave its 16)
        if (wave == 0) {                     // k rows (identical across waves)
            npb[64 + lane]      = sk0;
            npb[64 + 16 + lane] = sk1;
            npb[64 + 32 + lane] = sk2;
            npb[64 + 48 + lane] = sk3;
        }
    }
    unsigned short* gbase = Gp + ((size_t)bh*7 + cx)*4096;
    #pragma unroll
    for (int j=0;j<4;j++)
        #pragma unroll
        for (int r=0;r<4;r++)
            gbase[(wave*16 + lg*4 + r)*64 + j*16 + lr] = f2bf(acc[j][r]);
}

// ---------------- attention stage 2: combine + softmax -> ATT; + X2p pad-ring zero ----------------
__global__ __launch_bounds__(256) void k_sm(const unsigned short* __restrict__ Gp, const float* __restrict__ Np,
                                            const float* __restrict__ temperature,
                                            const float* __restrict__ rpb,
                                            unsigned short* __restrict__ ATT,
                                            unsigned short* __restrict__ X2p) {
    int bh = blockIdx.x; int h = bh % HEADS;
    int t = threadIdx.x;
    __shared__ float snorm[128];
    if (t < 128) {
        float s = 0.f;
        #pragma unroll
        for (int cx=0;cx<7;cx++) s += Np[((size_t)bh*7 + cx)*128 + t];
        snorm[t] = fmaxf(sqrtf(s), 1e-12f);
    }
    __syncthreads();
    int dq = t >> 2, de0 = (t & 3) * 16;
    float g[16];
    #pragma unroll
    for (int e=0;e<16;e++) g[e] = 0.f;
    #pragma unroll
    for (int cx=0;cx<7;cx++) {
        const unsigned short* base = Gp + ((size_t)bh*7 + cx)*4096 + dq*64 + de0;
        short8 v0 = *(const short8*)base;
        short8 v1 = *(const short8*)(base + 8);
        #pragma unroll
        for (int e=0;e<8;e++) g[e]   += bf2f((unsigned short)v0[e]);
        #pragma unroll
        for (int e=0;e<8;e++) g[8+e] += bf2f((unsigned short)v1[e]);
    }
    float temp = temperature[h];
    float bias = rpb[HEADS + h];
    float qn = snorm[dq];
    float lv[16]; float mx = -1e30f;
    #pragma unroll
    for (int e=0;e<16;e++) {
        int de = de0 + e;
        float v = g[e] / (qn * snorm[64 + de]) * temp + bias;
        lv[e] = v; mx = fmaxf(mx, v);
    }
    mx = fmaxf(mx, __shfl_xor(mx, 1, 64));
    mx = fmaxf(mx, __shfl_xor(mx, 2, 64));
    float se = 0.f;
    #pragma unroll
    for (int e=0;e<16;e++) { lv[e] = __expf(lv[e]-mx); se += lv[e]; }
    se += __shfl_xor(se, 1, 64);
    se += __shfl_xor(se, 2, 64);
    float inv = 1.0f/se;
    unsigned short pk[16];
    #pragma unroll
    for (int e=0;e<16;e++) pk[e] = f2bf(lv[e]*inv);
    unsigned short* dst = ATT + ((size_t)bh*64 + dq)*64 + de0;
    *(short8*)dst       = *(short8*)pk;
    *(short8*)(dst + 8) = *(short8*)(pk + 8);

    // ---- X2p pad-ring zero (Q/K dead after k_qk; 96 blocks = 16 b x 6 parts) ----
    int pb = bh / 6, part = bh % 6;
    unsigned short* base2 = X2p + (size_t)pb*NP*DIM;
    short8 z = {0,0,0,0,0,0,0,0};
    for (int task = part*256 + t; task < 10944; task += 1536) {
        int pos = task / 48, seg = task - pos*48;
        int py, px;
        if (pos < 58)       { py = 0;  px = pos; }
        else if (pos < 116) { py = 57; px = pos - 58; }
        else if (pos < 172) { py = pos - 115; px = 0; }
        else                { py = pos - 171; px = 57; }
        *(short8*)(base2 + ((size_t)(py*HP + px))*DIM + seg*8) = z;
    }
}

// ---------------- PV: XCA[b][n][h*64+dd] = sum_e ATT[dd][e] * V[e][n] ----------------
__global__ __launch_bounds__(256) void k_pv(const unsigned short* __restrict__ ATT,
                                            const unsigned short* __restrict__ Vt,
                                            unsigned short* __restrict__ XCA) {
    int nt = blockIdx.x, bh = blockIdx.y;
    int b = bh / HEADS, h = bh % HEADS;
    int t = threadIdx.x, wave = t >> 6, lane = t & 63;
    int lr = lane & 15, lg = lane >> 4;
    int n0 = nt*64;
    __shared__ float ctP[64][67];
    f32x4 acc[4];
    for (int i=0;i<4;i++) acc[i] = (f32x4){0.f,0.f,0.f,0.f};
    for (int ks=0; ks<2; ks++) {
        short8 bfr = *reinterpret_cast<const short8*>(Vt + ((size_t)bh*NN + n0 + wave*16 + lr)*64 + ks*32 + lg*8);
        for (int i=0;i<4;i++) {
            short8 a = *reinterpret_cast<const short8*>(ATT + ((size_t)bh*64 + i*16 + lr)*64 + ks*32 + lg*8);
            acc[i] = __builtin_amdgcn_mfma_f32_16x16x32_bf16(a, bfr, acc[i], 0, 0, 0);
        }
    }
    int nl = wave*16 + lr;
    #pragma unroll
    for (int i=0;i<4;i++)
        #pragma unroll
        for (int r=0;r<4;r++) ctP[nl][i*16 + lg*4 + r] = acc[i][r];
    __syncthreads();
    for (int q = t; q < 512; q += 256) {   // 64 n-rows x 8 dd-segs(8)
        int row = q >> 3, seg = q & 7;
        unsigned short pk[8];
        #pragma unroll
        for (int e=0;e<8;e++) pk[e] = f2bf(ctP[row][seg*8+e]);
        *(short8*)(XCA + ((size_t)(b*NN + n0 + row))*DIM + h*64 + seg*8) = *(short8*)pk;
    }
}

// ---------------- final: out = x + gamma-shuffled residual (Y bf16) ----------------
__global__ __launch_bounds__(256) void k_final(const float* __restrict__ x, const unsigned short* __restrict__ Yb,
                                               const float* __restrict__ gamma, float* __restrict__ out) {
    int i = blockIdx.x, b = blockIdx.y, kc = blockIdx.z;
    __shared__ float tile[56*193];
    int t = threadIdx.x;
    int k0 = kc*192;
    const unsigned short* ybase = Yb + (size_t)b*DIM*NN + (size_t)i*21504 + k0;
    for (int q = t; q < 56*24; q += 256) {
        int j = q / 24, c8 = (q % 24) * 8;
        short8 v = *(const short8*)(ybase + (size_t)j*384 + c8);
        float* dst = &tile[j*193 + c8];
        #pragma unroll
        for (int e=0;e<8;e++) dst[e] = bf2f((unsigned short)v[e]);
    }
    __syncthreads();
    for (int q = t; q < 192*56; q += 256) {
        int kl = q / 56, j = q % 56;
        int k = k0 + kl;
        size_t gi = ((size_t)(b*DIM + k))*NN + (size_t)i*56 + j;
        out[gi] = x[gi] + gamma[k] * tile[j*193 + kl];
    }
}

extern "C" void kernel_launch(void* const* d_in, const int* in_sizes, int n_in,
                              void* d_out, int out_size, void* d_ws, size_t ws_size,
                              hipStream_t stream) {
    const float* x       = (const float*)d_in[0];
    const float* pos_w   = (const float*)d_in[1];
    const float* pos_b   = (const float*)d_in[2];
    const float* ln_g    = (const float*)d_in[3];
    const float* ln_b    = (const float*)d_in[4];
    const float* gxca    = (const float*)d_in[5];
    const float* temp    = (const float*)d_in[6];
    const float* qkv_w   = (const float*)d_in[7];
    const float* qkv_b   = (const float*)d_in[8];
    const float* proj_w  = (const float*)d_in[9];
    const float* proj_b  = (const float*)d_in[10];
    const float* rpb     = (const float*)d_in[11];
    const float* conv_w  = (const float*)d_in[12];
    const float* bn_g    = (const float*)d_in[13];
    const float* bn_b    = (const float*)d_in[14];
    const float* bn_mean = (const float*)d_in[15];
    const float* bn_var  = (const float*)d_in[16];
    const float* gamma   = (const float*)d_in[17];
    float* out = (float*)d_out;
    char* ws = (char*)d_ws;

    const size_t oP   = 0;                        // P: 4,816,896 B
    const size_t oXT  = oP   + 4816896;           // XTb bf16 38.5MB (reused as Y bf16 after proj)
    const size_t oXN  = oXT  + 77070336;          // XN bf16: 38,535,168 B   (reused as Gp/Np, then XCA)
    const size_t oQ   = oXN  + 38535168;          // Qb bf16                  (reused as X2p padded, spans into Kb)
    const size_t oK   = oQ   + 38535168;          // Kb bf16
    const size_t oV   = oK   + 38535168;          // Vt bf16
    const size_t oATT = oV   + 38535168;          // ATT bf16: 786,432 B
    const size_t oWq  = oATT + 786432;            // 884,736 B
    const size_t oWp  = oWq  + 884736;            // 294,912 B
    const size_t oWc  = oWp  + 294912;            // 2,654,208 B

    float* P            = (float*)(ws + oP);
    unsigned short* XTb = (unsigned short*)(ws + oXT);
    unsigned short* Yb  = (unsigned short*)(ws + oXT);  // alias (XTb dead after proj epilogue)
    unsigned short* XN  = (unsigned short*)(ws + oXN);
    unsigned short* Gp  = (unsigned short*)(ws + oXN);      // alias (XN dead after qkv GEMM): 5,505,024 B
    float* Np           = (float*)(ws + oXN + 5505024);     // 344,064 B
    unsigned short* XCA = (unsigned short*)(ws + oXN);      // alias (Gp/Np dead after k_sm)
    unsigned short* Qb  = (unsigned short*)(ws + oQ);
    unsigned short* X2p = (unsigned short*)(ws + oQ);   // alias (Qb+Kb dead after k_qk)
    unsigned short* Kb  = (unsigned short*)(ws + oK);
    unsigned short* Vt  = (unsigned short*)(ws + oV);
    unsigned short* ATT = (unsigned short*)(ws + oATT);
    unsigned short* Wq  = (unsigned short*)(ws + oWq);
    unsigned short* Wp  = (unsigned short*)(ws + oWp);
    unsigned short* Wc  = (unsigned short*)(ws + oWc);

    k_prep<<<NN + 256, 256, 0, stream>>>(qkv_w, proj_w, conv_w, pos_w, pos_b, Wq, Wp, Wc, P);
    k_tln<<<BB*98, 256, 0, stream>>>(x, P, ln_g, ln_b, XTb, XN);
    k_gemm<0><<<3528, 256, 0, stream>>>(XN, Wq, qkv_b,
        Qb, Kb, Vt, nullptr, nullptr, nullptr);
    k_qk<<<dim3(7, BH), 256, 0, stream>>>(Qb, Kb, Gp, Np);
    k_sm<<<BH, 256, 0, stream>>>(Gp, Np, temp, rpb, ATT, X2p);
    k_pv<<<dim3(49, BH), 256, 0, stream>>>(ATT, Vt, XCA);
    k_gemm<1><<<1176, 256, 0, stream>>>(XCA, Wp, proj_b,
        nullptr, nullptr, nullptr, XTb, gxca, X2p);
    k_conv<<<1200, 256, 0, stream>>>(X2p, Wc, bn_g, bn_b, bn_mean, bn_var, Yb);
    k_final<<<dim3(56, BB, 2), 256, 0, stream>>>(x, Yb, gamma, out);
}

// Round 12
// 430.050 us; speedup vs baseline: 1.4548x; 1.0227x over previous
//
#include <hip/hip_runtime.h>
#include <hip/hip_bf16.h>
#include <math.h>

#define DIM 384
#define HEADS 6
#define NN 3136
#define BB 16
#define BH (BB*HEADS)
#define HP 58
#define NP (HP*HP)   // 3364 padded image

typedef __attribute__((ext_vector_type(8))) short short8;
typedef __attribute__((ext_vector_type(4))) short short4v;
typedef __attribute__((ext_vector_type(4))) float f32x4;

__device__ __forceinline__ float bf2f(unsigned short u) {
    union { unsigned int i; float f; } v; v.i = ((unsigned int)u) << 16; return v.f;
}
__device__ __forceinline__ unsigned short f2bf(float f) {
    union { float f; unsigned int i; } v; v.f = f;
    unsigned int r = v.i + 0x7fffu + ((v.i >> 16) & 1u);
    return (unsigned short)(r >> 16);
}
__device__ __forceinline__ void glds16(const unsigned short* g, void* l) {
    __builtin_amdgcn_global_load_lds(
        (const __attribute__((address_space(1))) unsigned int*)g,
        (__attribute__((address_space(3))) unsigned int*)l, 16, 0, 0);
}

// ---------------- fused prep: pos table (blocks 0..NN-1) + weight convert ----------------
__global__ void k_prep(const float* __restrict__ qkv_w, const float* __restrict__ proj_w,
                       const float* __restrict__ conv_w,
                       const float* __restrict__ pos_w, const float* __restrict__ pos_b,
                       unsigned short* __restrict__ Wq, unsigned short* __restrict__ Wp,
                       unsigned short* __restrict__ Wc, float* __restrict__ P) {
    int t = threadIdx.x;
    if (blockIdx.x < NN) {
        int n = blockIdx.x; int h = n / 56, w = n % 56;
        __shared__ float feat[64];
        if (t < 64) {
            int axis = t >> 5;      // 0 = y (h), 1 = x (w)
            int k = t & 31; int i = k >> 1;
            float e = (float)((axis ? w : h) + 1) / 56.000001f * 6.28318530717958647692f;
            float arg = e / powf(10000.0f, (float)i / 16.0f);
            feat[t] = (k & 1) ? cosf(arg) : sinf(arg);
        }
        __syncthreads();
        for (int c = t; c < DIM; c += 256) {
            float s = pos_b[c];
            #pragma unroll 8
            for (int k = 0; k < 64; k++) s += feat[k] * pos_w[c*64 + k];
            P[(size_t)n*DIM + c] = s;
        }
    } else {
        int tid = (blockIdx.x - NN) * 256 + t;
        int stride = 256 * 256;
        for (int i = tid; i < 3*DIM*DIM; i += stride) Wq[i] = f2bf(qkv_w[i]);
        for (int i = tid; i < DIM*DIM; i += stride) Wp[i] = f2bf(proj_w[i]);
        for (int i = tid; i < DIM*DIM*9; i += stride) {
            int ii = i % DIM; int rest = i / DIM; int tap = rest % 9; int o = rest / 9;
            Wc[i] = f2bf(conv_w[(size_t)(o*DIM + ii)*9 + tap]);
        }
    }
}

// ---------------- fused transpose + pos add + layernorm (short8 stores) ----------------
__global__ __launch_bounds__(256) void k_tln(const float* __restrict__ x, const float* __restrict__ P,
                                             const float* __restrict__ g, const float* __restrict__ be,
                                             unsigned short* __restrict__ XTb, unsigned short* __restrict__ XN) {
    __shared__ float tile[32][388];
    int blk = blockIdx.x;
    int b = blk / 98, nt = blk % 98;
    int n0 = nt*32;
    int t = threadIdx.x;
    #pragma unroll
    for (int it = 0; it < 12; it++) {
        int task = it*256 + t;
        int c = task >> 3, seg = task & 7;
        float4 v = *reinterpret_cast<const float4*>(x + ((size_t)(b*DIM + c))*NN + n0 + seg*4);
        tile[seg*4+0][c] = v.x; tile[seg*4+1][c] = v.y;
        tile[seg*4+2][c] = v.z; tile[seg*4+3][c] = v.w;
    }
    __syncthreads();
    int row = t >> 3, sub = t & 7;
    int n = n0 + row;
    float xp[48];
    float s = 0.f;
    #pragma unroll
    for (int k = 0; k < 6; k++) {
        int c0 = (k*8 + sub)*8;
        float4 tv0 = *reinterpret_cast<float4*>(&tile[row][c0]);
        float4 tv1 = *reinterpret_cast<float4*>(&tile[row][c0+4]);
        float4 pv0 = *reinterpret_cast<const float4*>(P + (size_t)n*DIM + c0);
        float4 pv1 = *reinterpret_cast<const float4*>(P + (size_t)n*DIM + c0 + 4);
        float v0 = tv0.x+pv0.x, v1 = tv0.y+pv0.y, v2 = tv0.z+pv0.z, v3 = tv0.w+pv0.w;
        float v4 = tv1.x+pv1.x, v5 = tv1.y+pv1.y, v6 = tv1.z+pv1.z, v7 = tv1.w+pv1.w;
        xp[k*8+0]=v0; xp[k*8+1]=v1; xp[k*8+2]=v2; xp[k*8+3]=v3;
        xp[k*8+4]=v4; xp[k*8+5]=v5; xp[k*8+6]=v6; xp[k*8+7]=v7;
        s += v0+v1+v2+v3+v4+v5+v6+v7;
        unsigned short pkx[8];
        pkx[0]=f2bf(v0); pkx[1]=f2bf(v1); pkx[2]=f2bf(v2); pkx[3]=f2bf(v3);
        pkx[4]=f2bf(v4); pkx[5]=f2bf(v5); pkx[6]=f2bf(v6); pkx[7]=f2bf(v7);
        *reinterpret_cast<short8*>(XTb + ((size_t)(b*NN + n))*DIM + c0) = *(short8*)pkx;
    }
    s += __shfl_xor(s, 1, 64); s += __shfl_xor(s, 2, 64); s += __shfl_xor(s, 4, 64);
    float mean = s * (1.0f/384.0f);
    float sq = 0.f;
    #pragma unroll
    for (int e = 0; e < 48; e++) { float d = xp[e]-mean; sq += d*d; }
    sq += __shfl_xor(sq, 1, 64); sq += __shfl_xor(sq, 2, 64); sq += __shfl_xor(sq, 4, 64);
    float rs = rsqrtf(sq * (1.0f/384.0f) + 1e-6f);
    #pragma unroll
    for (int k = 0; k < 6; k++) {
        int c0 = (k*8 + sub)*8;
        unsigned short pk[8];
        #pragma unroll
        for (int e = 0; e < 8; e++)
            pk[e] = f2bf((xp[k*8+e]-mean)*rs*g[c0+e] + be[c0+e]);
        *reinterpret_cast<short8*>(XN + ((size_t)(b*NN + n))*DIM + c0) = *(short8*)pk;
    }
}

// ---------------- MFMA GEMM (K=384): MODE 0 = qkv, 1 = proj ----------------
// A+B dbuf via swizzled global_load_lds; counted-vmcnt raw barriers (T4) + setprio (T5).
// Single-pass bf16 LDS epilogue staging (bias folded at stage time).
template<int MODE>
__global__ __launch_bounds__(256) void k_gemm(
    const unsigned short* __restrict__ A, const unsigned short* __restrict__ Wt,
    const float* __restrict__ bias,
    unsigned short* __restrict__ Qb, unsigned short* __restrict__ Kb, unsigned short* __restrict__ Vt,
    const unsigned short* __restrict__ XTb, const float* __restrict__ gxca, unsigned short* __restrict__ X2p)
{
    __shared__ __align__(16) char smem[35328];
    auto ctS = (unsigned short(*)[132])smem;           // [128][132] bf16 staging (33792 B)

    constexpr int NCT = (MODE == 0) ? 9 : 3;
    constexpr int CPX = (MODE == 0) ? 441 : 147;       // 392*NCT/8
    int bid = blockIdx.x;
    int orig = (bid & 7)*CPX + (bid >> 3);
    int ct = orig % NCT, mt = orig / NCT;
    int m0 = mt*128, o0 = ct*128;
    int t = threadIdx.x;
    int wave = t >> 6, lane = t & 63;
    int wr = wave >> 1, wc = wave & 1;
    int lr = lane & 15, lg = lane >> 4;

    int r0 = t >> 2;
    int swcol = (((t & 3) ^ ((t >> 3) & 3)) << 3);
    const unsigned short* a0 = A  + (size_t)(m0 + r0)*384 + swcol;
    const unsigned short* a1 = A  + (size_t)(m0 + 64 + r0)*384 + swcol;
    const unsigned short* b0 = Wt + (size_t)(o0 + r0)*384 + swcol;
    const unsigned short* b1 = Wt + (size_t)(o0 + 64 + r0)*384 + swcol;
    int rsw = ((lr >> 1) & 3) << 3;    // read-side swizzle (shorts)

    auto stage = [&](char* base, int c) {
        glds16(a0 + c, base + wave*1024);
        glds16(a1 + c, base + 4096 + wave*1024);
        glds16(b0 + c, base + 8192 + wave*1024);
        glds16(b1 + c, base + 12288 + wave*1024);
    };

    f32x4 acc[4][4];
    #pragma unroll
    for (int i=0;i<4;i++) for (int j=0;j<4;j++) acc[i][j] = (f32x4){0.f,0.f,0.f,0.f};

    stage(smem, 0);
    for (int kk = 0; kk < 12; kk++) {
        if (kk < 11) {
            stage(smem + ((kk+1)&1)*16384, (kk+1)*32);
            asm volatile("s_waitcnt vmcnt(4)" ::: "memory");
        } else {
            asm volatile("s_waitcnt vmcnt(0)" ::: "memory");
        }
        __builtin_amdgcn_s_barrier();
        __builtin_amdgcn_sched_barrier(0);
        auto As = (unsigned short(*)[32])(smem + (kk&1)*16384);
        auto Bs = (unsigned short(*)[32])(smem + (kk&1)*16384 + 8192);
        short8 af[4], bfv[4];
        #pragma unroll
        for (int i=0;i<4;i++) af[i]  = *(short8*)&As[wr*64 + i*16 + lr][(lg*8) ^ rsw];
        #pragma unroll
        for (int j=0;j<4;j++) bfv[j] = *(short8*)&Bs[wc*64 + j*16 + lr][(lg*8) ^ rsw];
        __builtin_amdgcn_s_setprio(1);
        #pragma unroll
        for (int i=0;i<4;i++)
            #pragma unroll
            for (int j=0;j<4;j++)
                acc[i][j] = __builtin_amdgcn_mfma_f32_16x16x32_bf16(af[i], bfv[j], acc[i][j], 0, 0, 0);
        __builtin_amdgcn_s_setprio(0);
        __builtin_amdgcn_s_barrier();
        __builtin_amdgcn_sched_barrier(0);
    }

    // ---- epilogue: single-pass bf16 staging, pure-copy write phases ----
    int comp = (MODE == 0) ? (o0 / DIM) : 0;
    constexpr bool M1 = (MODE == 1);
    bool useB = M1 || (MODE == 0 && comp == 2);
    float bv[4];
    #pragma unroll
    for (int j=0;j<4;j++) bv[j] = bias[o0 + wc*64 + j*16 + lr];
    if (useB) {
        // [m][o] orientation
        #pragma unroll
        for (int i=0;i<4;i++)
            #pragma unroll
            for (int j=0;j<4;j++)
                #pragma unroll
                for (int r=0;r<4;r++)
                    ctS[wr*64 + i*16 + lg*4 + r][wc*64 + j*16 + lr] = f2bf(acc[i][j][r] + bv[j]);
    } else {
        // [o][m] orientation, packed b64 writes along m
        #pragma unroll
        for (int j=0;j<4;j++)
            #pragma unroll
            for (int i=0;i<4;i++) {
                unsigned short p4[4];
                #pragma unroll
                for (int r=0;r<4;r++) p4[r] = f2bf(acc[i][j][r] + bv[j]);
                *(short4v*)&ctS[wc*64 + j*16 + lr][wr*64 + i*16 + lg*4] = *(short4v*)p4;
            }
    }
    __syncthreads();
    if (MODE == 1) {
        for (int q = t; q < 2048; q += 256) {   // 128 m-rows x 16 o-segs(8)
            int row = q >> 4, seg = q & 15;
            int m = m0 + row; int b = m/NN; int n = m - b*NN;
            int py = n/56, px = n - py*56;
            int og0 = o0 + seg*8;
            short8 sv  = *(short8*)&ctS[row][seg*8];
            short8 xvb = *(const short8*)(XTb + (size_t)m*DIM + og0);
            unsigned short pk[8];
            #pragma unroll
            for (int e=0;e<8;e++)
                pk[e] = f2bf(bf2f((unsigned short)xvb[e]) + gxca[og0+e]*bf2f((unsigned short)sv[e]));
            *(short8*)(X2p + ((size_t)(b*NP + (py+1)*HP + px + 1))*DIM + og0) = *(short8*)pk;
        }
    } else if (comp < 2) {                      // Q / K: (bh,dd,N) layout, pure copy
        unsigned short* Dst = (comp == 0) ? Qb : Kb;
        for (int q = t; q < 4096; q += 256) {   // 128 o-rows x 32 m-segs(4)
            int row = q >> 5, seg = q & 31;
            int og = o0 + row; int rem = og - comp*DIM;
            int hh = rem >> 6, dd = rem & 63;
            int m4 = m0 + seg*4; int b = m4/NN; int n = m4 - b*NN;
            *(short4v*)(Dst + ((size_t)((b*HEADS + hh)*64 + dd))*NN + n) = *(short4v*)&ctS[row][seg*4];
        }
    } else {                                    // V: (bh,N,dd) layout, pure copy
        for (int q = t; q < 2048; q += 256) {   // 128 m-rows x 16 o-segs(8)
            int row = q >> 4, seg = q & 15;
            int m = m0 + row; int b = m/NN; int n = m - b*NN;
            int og0 = o0 + seg*8; int rem0 = og0 - 2*DIM;
            int hh = rem0 >> 6, dd0 = rem0 & 63;
            *(short8*)(Vt + ((size_t)((b*HEADS + hh)*NN + n))*64 + dd0) = *(short8*)&ctS[row][seg*8];
        }
    }
}

// ---------------- conv3x3 + BN + SiLU + residual, counted-vmcnt pipeline + setprio ----------------
__global__ __launch_bounds__(256, 3) void k_conv(
    const unsigned short* __restrict__ A, const unsigned short* __restrict__ Wt,
    const float* __restrict__ bn_g, const float* __restrict__ bn_b,
    const float* __restrict__ bn_mean, const float* __restrict__ bn_var,
    unsigned short* __restrict__ Yout)
{
    __shared__ __align__(16) char smem[49152];
    // k-loop: A halo dbuf 2x[256][32] @0 (32KB), B dbuf 2x[128][32] @32768 (16KB)
    auto ctA = (float(*)[69])smem;                     // epilogue alias [64][69] 17664
    auto X2s = (unsigned short(*)[68])(smem + 17664);  // [64][68] 8704

    int bid = blockIdx.x;                 // 1200 = 8*150
    int orig = (bid & 7)*150 + (bid >> 3);
    int ct = orig % 3; int rest = orig / 3;
    int tile = rest % 25; int b = rest / 25;
    int n0 = tile*128, o0 = ct*128;
    int t = threadIdx.x;
    int wave = t >> 6, lane = t & 63;
    int wr = wave >> 1, wc = wave & 1;
    int lr = lane & 15, lg = lane >> 4;
    int qb = n0 + 2*(n0/56);
    const size_t bbase = (size_t)b*NP*DIM;

    int swcol = (((t & 3) ^ ((t >> 3) & 3)) << 3);
    const unsigned short* asrc[4];
    #pragma unroll
    for (int j=0;j<4;j++) {
        int task = j*256 + t;
        int row = task >> 2;
        int q = qb + row; if (q > NP-1) q = NP-1;
        asrc[j] = A + bbase + (size_t)q*DIM + swcol;
    }
    const unsigned short* bsrc0 = Wt + (size_t)(o0 + (t>>2))*3456 + swcol;
    const unsigned short* bsrc1 = Wt + (size_t)(o0 + 64 + (t>>2))*3456 + swcol;

    int qrel[4];
    #pragma unroll
    for (int i=0;i<4;i++) {
        int loc = wr*64 + i*16 + lr;
        int n = n0 + loc; if (n >= NN) n = NN-1;
        qrel[i] = n + 2*(n/56) - qb;
    }

    auto stageA = [&](int bufsel, int c) {
        #pragma unroll
        for (int j=0;j<4;j++) glds16(asrc[j] + c, smem + bufsel*16384 + j*4096 + wave*1024);
    };
    auto stageB = [&](int slot, int off) {
        glds16(bsrc0 + off, smem + 32768 + slot*8192 + wave*1024);
        glds16(bsrc1 + off, smem + 32768 + slot*8192 + 4096 + wave*1024);
    };

    f32x4 acc[4][4];
    #pragma unroll
    for (int i=0;i<4;i++) for (int j=0;j<4;j++) acc[i][j] = (f32x4){0.f,0.f,0.f,0.f};

    stageA(0, 0); stageB(0, 0);
    for (int kk = 0; kk < 12; kk++) {
        auto Ah = (unsigned short(*)[32])(smem + (kk&1)*16384);
        #pragma unroll
        for (int tap = 0; tap < 9; tap++) {
            if (kk < 11 || tap < 8) {
                int off = (tap < 8) ? ((tap+1)*384 + kk*32) : ((kk+1)*32);
                stageB((kk+tap+1)&1, off);
            }
            if (tap == 6 && kk < 11) stageA((kk+1)&1, (kk+1)*32);
            if (kk < 11 && (tap == 6 || tap == 7))
                asm volatile("s_waitcnt vmcnt(6)" ::: "memory");
            else if (kk == 11 && tap == 8)
                asm volatile("s_waitcnt vmcnt(0)" ::: "memory");
            else
                asm volatile("s_waitcnt vmcnt(2)" ::: "memory");
            __builtin_amdgcn_s_barrier();
            __builtin_amdgcn_sched_barrier(0);
            auto Bs = (unsigned short(*)[32])(smem + 32768 + ((kk+tap)&1)*8192);
            int toff = (tap/3)*58 + (tap%3);
            short8 af[4], bfv[4];
            #pragma unroll
            for (int j=0;j<4;j++) {
                int brow = wc*64 + j*16 + lr;
                bfv[j] = *(short8*)&Bs[brow][(lg*8) ^ (((brow>>1)&3)<<3)];
            }
            #pragma unroll
            for (int i=0;i<4;i++) {
                int row = qrel[i] + toff;
                af[i] = *(short8*)&Ah[row][(lg*8) ^ (((row>>1)&3)<<3)];
            }
            __builtin_amdgcn_s_setprio(1);
            #pragma unroll
            for (int i=0;i<4;i++)
                #pragma unroll
                for (int j=0;j<4;j++)
                    acc[i][j] = __builtin_amdgcn_mfma_f32_16x16x32_bf16(af[i], bfv[j], acc[i][j], 0, 0, 0);
            __builtin_amdgcn_s_setprio(0);
            __builtin_amdgcn_s_barrier();
            __builtin_amdgcn_sched_barrier(0);
        }
    }

    // ---- epilogue: 4 quadrant passes (mh x oh), coalesced bf16 short8 writes ----
    for (int mh = 0; mh < 2; mh++) {
        for (int oh = 0; oh < 2; oh++) {
            __syncthreads();
            if (wr == mh && wc == oh) {
                #pragma unroll
                for (int i=0;i<4;i++) for (int j=0;j<4;j++) for (int r=0;r<4;r++)
                    ctA[j*16 + lr][i*16 + lg*4 + r] = acc[i][j][r];
            }
            for (int q = t; q < 512; q += 256) {    // residual: 64 m-rows x 8 o-segs(8)
                int row = q >> 3, sg = q & 7;
                int n = n0 + mh*64 + row; int nc = (n < NN) ? n : NN-1;
                int qq = nc + 2*(nc/56) + 59;       // center tap (+1,+1)
                short8 v = *(const short8*)(A + bbase + (size_t)qq*DIM + o0 + oh*64 + sg*8);
                short4v lo = {v[0],v[1],v[2],v[3]}, hi = {v[4],v[5],v[6],v[7]};
                *(short4v*)&X2s[row][sg*8]     = lo;
                *(short4v*)&X2s[row][sg*8 + 4] = hi;
            }
            __syncthreads();
            for (int q = t; q < 512; q += 256) {    // 64 o-rows x 8 n-segs(8)
                int orow = q >> 3, sg = q & 7;
                int o = o0 + oh*64 + orow;
                int n = n0 + mh*64 + sg*8;
                if (n < NN) {
                    float mean = bn_mean[o], rs = rsqrtf(bn_var[o] + 1e-5f);
                    float gg = bn_g[o], bb2 = bn_b[o];
                    unsigned short pk[8];
                    #pragma unroll
                    for (int e=0;e<8;e++) {
                        float xi = (ctA[orow][sg*8+e] - mean)*rs*gg + bb2;
                        float si = xi / (1.0f + __expf(-xi));
                        pk[e] = f2bf(si + bf2f(X2s[sg*8+e][orow]));
                    }
                    *(short8*)(Yout + ((size_t)(b*DIM + o))*NN + n) = *(short8*)pk;
                }
            }
        }
    }
}

// ---------------- attention stage 1: partial G = q k^T (bf16 out) + FUSED sq-norms ----------------
__global__ __launch_bounds__(256) void k_qk(const unsigned short* __restrict__ Qb,
                                            const unsigned short* __restrict__ Kb,
                                            unsigned short* __restrict__ Gp, float* __restrict__ Np) {
    int cx = blockIdx.x, bh = blockIdx.y;
    int t = threadIdx.x, wave = t >> 6, lane = t & 63;
    int lr = lane & 15, lg = lane >> 4;
    f32x4 acc[4];
    #pragma unroll
    for (int j=0;j<4;j++) acc[j] = (f32x4){0.f,0.f,0.f,0.f};
    float sq = 0.f;
    float sk0 = 0.f, sk1 = 0.f, sk2 = 0.f, sk3 = 0.f;
    const unsigned short* qrow = Qb + ((size_t)bh*64 + wave*16 + lr)*NN + cx*448;
    const unsigned short* kbase = Kb + (size_t)bh*64*NN + cx*448;
    for (int ks = 0; ks < 14; ks++) {
        short8 a = *(const short8*)(qrow + ks*32 + lg*8);
        #pragma unroll
        for (int e=0;e<8;e++) { float f = bf2f((unsigned short)a[e]); sq += f*f; }
        #pragma unroll
        for (int j=0;j<4;j++) {
            short8 bfr = *(const short8*)(kbase + (size_t)(j*16+lr)*NN + ks*32 + lg*8);
            float* skp = (j==0)?&sk0:(j==1)?&sk1:(j==2)?&sk2:&sk3;
            float sloc = 0.f;
            #pragma unroll
            for (int e=0;e<8;e++) { float f = bf2f((unsigned short)bfr[e]); sloc += f*f; }
            *skp += sloc;
            acc[j] = __builtin_amdgcn_mfma_f32_16x16x32_bf16(a, bfr, acc[j], 0, 0, 0);
        }
    }
    sq  += __shfl_xor(sq, 16, 64);  sq  += __shfl_xor(sq, 32, 64);
    sk0 += __shfl_xor(sk0, 16, 64); sk0 += __shfl_xor(sk0, 32, 64);
    sk1 += __shfl_xor(sk1, 16, 64); sk1 += __shfl_xor(sk1, 32, 64);
    sk2 += __shfl_xor(sk2, 16, 64); sk2 += __shfl_xor(sk2, 32, 64);
    sk3 += __shfl_xor(sk3, 16, 64); sk3 += __shfl_xor(sk3, 32, 64);
    float* npb = Np + ((size_t)bh*7 + cx)*128;
    if (lane < 16) {
        npb[wave*16 + lane] = sq;            // q rows (each wave its 16)
        if (wave == 0) {                     // k rows (identical across waves)
            npb[64 + lane]      = sk0;
            npb[64 + 16 + lane] = sk1;
            npb[64 + 32 + lane] = sk2;
            npb[64 + 48 + lane] = sk3;
        }
    }
    unsigned short* gbase = Gp + ((size_t)bh*7 + cx)*4096;
    #pragma unroll
    for (int j=0;j<4;j++)
        #pragma unroll
        for (int r=0;r<4;r++)
            gbase[(wave*16 + lg*4 + r)*64 + j*16 + lr] = f2bf(acc[j][r]);
}

// ---------------- attention stage 2: combine + softmax -> ATT; + X2p pad-ring zero ----------------
__global__ __launch_bounds__(256) void k_sm(const unsigned short* __restrict__ Gp, const float* __restrict__ Np,
                                            const float* __restrict__ temperature,
                                            const float* __restrict__ rpb,
                                            unsigned short* __restrict__ ATT,
                                            unsigned short* __restrict__ X2p) {
    int bh = blockIdx.x; int h = bh % HEADS;
    int t = threadIdx.x;
    __shared__ float snorm[128];
    if (t < 128) {
        float s = 0.f;
        #pragma unroll
        for (int cx=0;cx<7;cx++) s += Np[((size_t)bh*7 + cx)*128 + t];
        snorm[t] = fmaxf(sqrtf(s), 1e-12f);
    }
    __syncthreads();
    int dq = t >> 2, de0 = (t & 3) * 16;
    float g[16];
    #pragma unroll
    for (int e=0;e<16;e++) g[e] = 0.f;
    #pragma unroll
    for (int cx=0;cx<7;cx++) {
        const unsigned short* base = Gp + ((size_t)bh*7 + cx)*4096 + dq*64 + de0;
        short8 v0 = *(const short8*)base;
        short8 v1 = *(const short8*)(base + 8);
        #pragma unroll
        for (int e=0;e<8;e++) g[e]   += bf2f((unsigned short)v0[e]);
        #pragma unroll
        for (int e=0;e<8;e++) g[8+e] += bf2f((unsigned short)v1[e]);
    }
    float temp = temperature[h];
    float bias = rpb[HEADS + h];
    float qn = snorm[dq];
    float lv[16]; float mx = -1e30f;
    #pragma unroll
    for (int e=0;e<16;e++) {
        int de = de0 + e;
        float v = g[e] / (qn * snorm[64 + de]) * temp + bias;
        lv[e] = v; mx = fmaxf(mx, v);
    }
    mx = fmaxf(mx, __shfl_xor(mx, 1, 64));
    mx = fmaxf(mx, __shfl_xor(mx, 2, 64));
    float se = 0.f;
    #pragma unroll
    for (int e=0;e<16;e++) { lv[e] = __expf(lv[e]-mx); se += lv[e]; }
    se += __shfl_xor(se, 1, 64);
    se += __shfl_xor(se, 2, 64);
    float inv = 1.0f/se;
    unsigned short pk[16];
    #pragma unroll
    for (int e=0;e<16;e++) pk[e] = f2bf(lv[e]*inv);
    unsigned short* dst = ATT + ((size_t)bh*64 + dq)*64 + de0;
    *(short8*)dst       = *(short8*)pk;
    *(short8*)(dst + 8) = *(short8*)(pk + 8);

    // ---- X2p pad-ring zero (Q/K dead after k_qk; 96 blocks = 16 b x 6 parts) ----
    int pb = bh / 6, part = bh % 6;
    unsigned short* base2 = X2p + (size_t)pb*NP*DIM;
    short8 z = {0,0,0,0,0,0,0,0};
    for (int task = part*256 + t; task < 10944; task += 1536) {
        int pos = task / 48, seg = task - pos*48;
        int py, px;
        if (pos < 58)       { py = 0;  px = pos; }
        else if (pos < 116) { py = 57; px = pos - 58; }
        else if (pos < 172) { py = pos - 115; px = 0; }
        else                { py = pos - 171; px = 57; }
        *(short8*)(base2 + ((size_t)(py*HP + px))*DIM + seg*8) = z;
    }
}

// ---------------- PV: XCA[b][n][h*64+dd] = sum_e ATT[dd][e] * V[e][n] ----------------
__global__ __launch_bounds__(256) void k_pv(const unsigned short* __restrict__ ATT,
                                            const unsigned short* __restrict__ Vt,
                                            unsigned short* __restrict__ XCA) {
    int nt = blockIdx.x, bh = blockIdx.y;
    int b = bh / HEADS, h = bh % HEADS;
    int t = threadIdx.x, wave = t >> 6, lane = t & 63;
    int lr = lane & 15, lg = lane >> 4;
    int n0 = nt*64;
    __shared__ float ctP[64][67];
    f32x4 acc[4];
    for (int i=0;i<4;i++) acc[i] = (f32x4){0.f,0.f,0.f,0.f};
    for (int ks=0; ks<2; ks++) {
        short8 bfr = *reinterpret_cast<const short8*>(Vt + ((size_t)bh*NN + n0 + wave*16 + lr)*64 + ks*32 + lg*8);
        for (int i=0;i<4;i++) {
            short8 a = *reinterpret_cast<const short8*>(ATT + ((size_t)bh*64 + i*16 + lr)*64 + ks*32 + lg*8);
            acc[i] = __builtin_amdgcn_mfma_f32_16x16x32_bf16(a, bfr, acc[i], 0, 0, 0);
        }
    }
    int nl = wave*16 + lr;
    #pragma unroll
    for (int i=0;i<4;i++)
        #pragma unroll
        for (int r=0;r<4;r++) ctP[nl][i*16 + lg*4 + r] = acc[i][r];
    __syncthreads();
    for (int q = t; q < 512; q += 256) {   // 64 n-rows x 8 dd-segs(8)
        int row = q >> 3, seg = q & 7;
        unsigned short pk[8];
        #pragma unroll
        for (int e=0;e<8;e++) pk[e] = f2bf(ctP[row][seg*8+e]);
        *(short8*)(XCA + ((size_t)(b*NN + n0 + row))*DIM + h*64 + seg*8) = *(short8*)pk;
    }
}

// ---------------- final: out = x + gamma-shuffled residual (Y bf16) ----------------
__global__ __launch_bounds__(256) void k_final(const float* __restrict__ x, const unsigned short* __restrict__ Yb,
                                               const float* __restrict__ gamma, float* __restrict__ out) {
    int i = blockIdx.x, b = blockIdx.y, kc = blockIdx.z;
    __shared__ float tile[56*193];
    int t = threadIdx.x;
    int k0 = kc*192;
    const unsigned short* ybase = Yb + (size_t)b*DIM*NN + (size_t)i*21504 + k0;
    for (int q = t; q < 56*24; q += 256) {
        int j = q / 24, c8 = (q % 24) * 8;
        short8 v = *(const short8*)(ybase + (size_t)j*384 + c8);
        float* dst = &tile[j*193 + c8];
        #pragma unroll
        for (int e=0;e<8;e++) dst[e] = bf2f((unsigned short)v[e]);
    }
    __syncthreads();
    for (int q = t; q < 192*56; q += 256) {
        int kl = q / 56, j = q % 56;
        int k = k0 + kl;
        size_t gi = ((size_t)(b*DIM + k))*NN + (size_t)i*56 + j;
        out[gi] = x[gi] + gamma[k] * tile[j*193 + kl];
    }
}

extern "C" void kernel_launch(void* const* d_in, const int* in_sizes, int n_in,
                              void* d_out, int out_size, void* d_ws, size_t ws_size,
                              hipStream_t stream) {
    const float* x       = (const float*)d_in[0];
    const float* pos_w   = (const float*)d_in[1];
    const float* pos_b   = (const float*)d_in[2];
    const float* ln_g    = (const float*)d_in[3];
    const float* ln_b    = (const float*)d_in[4];
    const float* gxca    = (const float*)d_in[5];
    const float* temp    = (const float*)d_in[6];
    const float* qkv_w   = (const float*)d_in[7];
    const float* qkv_b   = (const float*)d_in[8];
    const float* proj_w  = (const float*)d_in[9];
    const float* proj_b  = (const float*)d_in[10];
    const float* rpb     = (const float*)d_in[11];
    const float* conv_w  = (const float*)d_in[12];
    const float* bn_g    = (const float*)d_in[13];
    const float* bn_b    = (const float*)d_in[14];
    const float* bn_mean = (const float*)d_in[15];
    const float* bn_var  = (const float*)d_in[16];
    const float* gamma   = (const float*)d_in[17];
    float* out = (float*)d_out;
    char* ws = (char*)d_ws;

    const size_t oP   = 0;                        // P: 4,816,896 B
    const size_t oXT  = oP   + 4816896;           // XTb bf16 38.5MB (reused as Y bf16 after proj)
    const size_t oXN  = oXT  + 77070336;          // XN bf16: 38,535,168 B   (reused as Gp/Np, then XCA)
    const size_t oQ   = oXN  + 38535168;          // Qb bf16                  (reused as X2p padded, spans into Kb)
    const size_t oK   = oQ   + 38535168;          // Kb bf16
    const size_t oV   = oK   + 38535168;          // Vt bf16
    const size_t oATT = oV   + 38535168;          // ATT bf16: 786,432 B
    const size_t oWq  = oATT + 786432;            // 884,736 B
    const size_t oWp  = oWq  + 884736;            // 294,912 B
    const size_t oWc  = oWp  + 294912;            // 2,654,208 B

    float* P            = (float*)(ws + oP);
    unsigned short* XTb = (unsigned short*)(ws + oXT);
    unsigned short* Yb  = (unsigned short*)(ws + oXT);  // alias (XTb dead after proj epilogue)
    unsigned short* XN  = (unsigned short*)(ws + oXN);
    unsigned short* Gp  = (unsigned short*)(ws + oXN);      // alias (XN dead after qkv GEMM): 5,505,024 B
    float* Np           = (float*)(ws + oXN + 5505024);     // 344,064 B
    unsigned short* XCA = (unsigned short*)(ws + oXN);      // alias (Gp/Np dead after k_sm)
    unsigned short* Qb  = (unsigned short*)(ws + oQ);
    unsigned short* X2p = (unsigned short*)(ws + oQ);   // alias (Qb+Kb dead after k_qk)
    unsigned short* Kb  = (unsigned short*)(ws + oK);
    unsigned short* Vt  = (unsigned short*)(ws + oV);
    unsigned short* ATT = (unsigned short*)(ws + oATT);
    unsigned short* Wq  = (unsigned short*)(ws + oWq);
    unsigned short* Wp  = (unsigned short*)(ws + oWp);
    unsigned short* Wc  = (unsigned short*)(ws + oWc);

    k_prep<<<NN + 256, 256, 0, stream>>>(qkv_w, proj_w, conv_w, pos_w, pos_b, Wq, Wp, Wc, P);
    k_tln<<<BB*98, 256, 0, stream>>>(x, P, ln_g, ln_b, XTb, XN);
    k_gemm<0><<<3528, 256, 0, stream>>>(XN, Wq, qkv_b,
        Qb, Kb, Vt, nullptr, nullptr, nullptr);
    k_qk<<<dim3(7, BH), 256, 0, stream>>>(Qb, Kb, Gp, Np);
    k_sm<<<BH, 256, 0, stream>>>(Gp, Np, temp, rpb, ATT, X2p);
    k_pv<<<dim3(49, BH), 256, 0, stream>>>(ATT, Vt, XCA);
    k_gemm<1><<<1176, 256, 0, stream>>>(XCA, Wp, proj_b,
        nullptr, nullptr, nullptr, XTb, gxca, X2p);
    k_conv<<<1200, 256, 0, stream>>>(X2p, Wc, bn_g, bn_b, bn_mean, bn_var, Yb);
    k_final<<<dim3(56, BB, 2), 256, 0, stream>>>(x, Yb, gamma, out);
}